// Round 1
// baseline (2496.099 us; speedup 1.0000x reference)
//
#include <hip/hip_runtime.h>
#include <math.h>

#define BB 8
#define NN 2048
#define LL 2048
#define CC 256
#define KK 16
#define NL 2
#define FF 4

// ---------------------------------------------------------------- copy
__global__ __launch_bounds__(256) void copy_k(const float* __restrict__ src,
                                              float* __restrict__ dst) {
    size_t i = (size_t)blockIdx.x * 256 + threadIdx.x;   // one float4 each
    reinterpret_cast<float4*>(dst)[i] = reinterpret_cast<const float4*>(src)[i];
}

// ---------------------------------------------------------------- knn
// One thread per query point; kv_xyz for the batch staged in LDS.
__global__ __launch_bounds__(256) void knn_k(const float* __restrict__ qxyz,
                                             const float* __restrict__ kvxyz,
                                             int* __restrict__ idx,
                                             float* __restrict__ valid) {
    __shared__ float s[LL * 3];
    const int b = blockIdx.x >> 3;
    const int n = ((blockIdx.x & 7) << 8) + threadIdx.x;
    const float* kb = kvxyz + (size_t)b * LL * 3;
    for (int t = threadIdx.x; t < LL * 3; t += 256) s[t] = kb[t];
    __syncthreads();

    const size_t q = (size_t)(b * NN + n) * 3;
    const float qx = qxyz[q], qy = qxyz[q + 1], qz = qxyz[q + 2];

    float bd[KK];
    int   bi[KK];
#pragma unroll
    for (int k = 0; k < KK; ++k) { bd[k] = 3e38f; bi[k] = 0; }
    float worst = 3e38f; int wslot = 0;

    for (int j = 0; j < LL; ++j) {
        float dx = qx - s[3 * j];
        float dy = qy - s[3 * j + 1];
        float dz = qz - s[3 * j + 2];
        float d2 = dx * dx + dy * dy + dz * dz;
        if (d2 < worst) {
            bd[wslot] = d2; bi[wslot] = j;
            worst = bd[0]; wslot = 0;
#pragma unroll
            for (int k = 1; k < KK; ++k)
                if (bd[k] > worst) { worst = bd[k]; wslot = k; }
        }
    }
    const float rad2 = (float)(0.12 * 0.12);
    const size_t o = (size_t)(b * NN + n) * KK;
#pragma unroll
    for (int k = 0; k < KK; ++k) {
        idx[o + k]   = bi[k];
        valid[o + k] = (bd[k] <= rad2) ? 1.0f : 0.0f;
    }
}

// ---------------------------------------------------------------- gemm
// C[M,N] = act(A[M,Kd] @ Bw[Kd,N] + bias). 128x128 tile, 256 thr, 8x8/thr.
template <int ACT>
__device__ __forceinline__ float actf(float x) {
    if (ACT == 1) return 0.5f * x * (1.0f + erff(x * 0.70710678118654752f));
    return x;
}

template <int ACT>
__global__ __launch_bounds__(256) void gemm_k(const float* __restrict__ A,
                                              const float* __restrict__ Bw,
                                              const float* __restrict__ bias,
                                              float* __restrict__ C,
                                              int M, int N, int Kd) {
    __shared__ float As[16][132];   // k-major, padded (stride 132 keeps 16B align)
    __shared__ float Bs[16][132];
    const int tid  = threadIdx.x;
    const int row0 = blockIdx.y * 128;
    const int col0 = blockIdx.x * 128;
    const int tx = tid & 15;    // col group
    const int ty = tid >> 4;    // row group

    const int ar = tid >> 1;          // staging: row within A tile
    const int ak = (tid & 1) * 8;     // k offset (0 or 8)
    const int bk = tid >> 4;          // staging: k row of B tile
    const int bc = (tid & 15) * 8;    // col offset

    float acc[8][8];
#pragma unroll
    for (int i = 0; i < 8; ++i)
#pragma unroll
        for (int j = 0; j < 8; ++j) acc[i][j] = 0.0f;

    for (int k0 = 0; k0 < Kd; k0 += 16) {
        __syncthreads();
        const float4* ap = reinterpret_cast<const float4*>(
            &A[(size_t)(row0 + ar) * Kd + k0 + ak]);
        float4 a0 = ap[0], a1 = ap[1];
        As[ak + 0][ar] = a0.x; As[ak + 1][ar] = a0.y;
        As[ak + 2][ar] = a0.z; As[ak + 3][ar] = a0.w;
        As[ak + 4][ar] = a1.x; As[ak + 5][ar] = a1.y;
        As[ak + 6][ar] = a1.z; As[ak + 7][ar] = a1.w;
        const float4* bp = reinterpret_cast<const float4*>(
            &Bw[(size_t)(k0 + bk) * N + col0 + bc]);
        float4 b0 = bp[0], b1 = bp[1];
        *reinterpret_cast<float4*>(&Bs[bk][bc])     = b0;
        *reinterpret_cast<float4*>(&Bs[bk][bc + 4]) = b1;
        __syncthreads();

#pragma unroll
        for (int kk = 0; kk < 16; ++kk) {
            float4 fa0 = *reinterpret_cast<const float4*>(&As[kk][ty * 8]);
            float4 fa1 = *reinterpret_cast<const float4*>(&As[kk][ty * 8 + 4]);
            float4 fb0 = *reinterpret_cast<const float4*>(&Bs[kk][tx * 4]);
            float4 fb1 = *reinterpret_cast<const float4*>(&Bs[kk][64 + tx * 4]);
            float av[8] = {fa0.x, fa0.y, fa0.z, fa0.w, fa1.x, fa1.y, fa1.z, fa1.w};
            float bv[8] = {fb0.x, fb0.y, fb0.z, fb0.w, fb1.x, fb1.y, fb1.z, fb1.w};
#pragma unroll
            for (int i = 0; i < 8; ++i)
#pragma unroll
                for (int j = 0; j < 8; ++j)
                    acc[i][j] = fmaf(av[i], bv[j], acc[i][j]);
        }
    }

    float bja[8];
    if (bias) {
        float4 g0 = *reinterpret_cast<const float4*>(&bias[col0 + tx * 4]);
        float4 g1 = *reinterpret_cast<const float4*>(&bias[col0 + 64 + tx * 4]);
        bja[0] = g0.x; bja[1] = g0.y; bja[2] = g0.z; bja[3] = g0.w;
        bja[4] = g1.x; bja[5] = g1.y; bja[6] = g1.z; bja[7] = g1.w;
    } else {
#pragma unroll
        for (int j = 0; j < 8; ++j) bja[j] = 0.0f;
    }

#pragma unroll
    for (int i = 0; i < 8; ++i) {
        const int r = row0 + ty * 8 + i;
        float4 o0, o1;
        o0.x = actf<ACT>(acc[i][0] + bja[0]);
        o0.y = actf<ACT>(acc[i][1] + bja[1]);
        o0.z = actf<ACT>(acc[i][2] + bja[2]);
        o0.w = actf<ACT>(acc[i][3] + bja[3]);
        o1.x = actf<ACT>(acc[i][4] + bja[4]);
        o1.y = actf<ACT>(acc[i][5] + bja[5]);
        o1.z = actf<ACT>(acc[i][6] + bja[6]);
        o1.w = actf<ACT>(acc[i][7] + bja[7]);
        *reinterpret_cast<float4*>(&C[(size_t)r * N + col0 + tx * 4])      = o0;
        *reinterpret_cast<float4*>(&C[(size_t)r * N + col0 + 64 + tx * 4]) = o1;
    }
}

// ---------------------------------------------------------------- fused attention
// One block per query (b,n); thread = output channel c. Per-channel softmax
// over K=16 neighbors happens entirely within one thread.
__global__ __launch_bounds__(256) void attn_k(const float* __restrict__ adst,
                                              const float* __restrict__ asrc,
                                              const float* __restrict__ vf,
                                              const int* __restrict__ idx,
                                              const float* __restrict__ valid,
                                              const float* __restrict__ Wat,
                                              const float* __restrict__ bat,
                                              float* __restrict__ conv) {
    const int bn = blockIdx.x;
    const int b  = bn >> 11;           // N = 2048
    const int c  = threadIdx.x;
    __shared__ float ds[KK][260];
    __shared__ int   sidx[KK];
    __shared__ float sv[KK];
    if (c < KK) {
        sidx[c] = idx[(size_t)bn * KK + c];
        sv[c]   = valid[(size_t)bn * KK + c];
    }
    __syncthreads();

    const float ad = adst[(size_t)bn * CC + c];
    const float* ab = asrc + (size_t)b * LL * CC;
#pragma unroll
    for (int k = 0; k < KK; ++k)
        ds[k][c] = ad - ab[(size_t)sidx[k] * CC + c];
    __syncthreads();

    float acc[KK];
    const float bias = bat[c];
#pragma unroll
    for (int k = 0; k < KK; ++k) acc[k] = bias;

    for (int j = 0; j < CC; j += 4) {
        const float w0 = Wat[(size_t)(j + 0) * CC + c];
        const float w1 = Wat[(size_t)(j + 1) * CC + c];
        const float w2 = Wat[(size_t)(j + 2) * CC + c];
        const float w3 = Wat[(size_t)(j + 3) * CC + c];
#pragma unroll
        for (int k = 0; k < KK; ++k) {
            float4 dv = *reinterpret_cast<const float4*>(&ds[k][j]);
            acc[k] = fmaf(dv.x, w0, acc[k]);
            acc[k] = fmaf(dv.y, w1, acc[k]);
            acc[k] = fmaf(dv.z, w2, acc[k]);
            acc[k] = fmaf(dv.w, w3, acc[k]);
        }
    }

    // logits: valid ? relu(acc) : -1e9
    float m = -1e9f;
#pragma unroll
    for (int k = 0; k < KK; ++k) {
        acc[k] = (sv[k] > 0.5f) ? fmaxf(acc[k], 0.0f) : -1e9f;
        m = fmaxf(m, acc[k]);
    }
    float s = 0.0f, cv = 0.0f;
    const float* vb = vf + (size_t)b * LL * CC;
#pragma unroll
    for (int k = 0; k < KK; ++k) {
        const float vk = vb[(size_t)sidx[k] * CC + c];
        const float e = (sv[k] > 0.5f) ? __expf(acc[k] - m) : 0.0f;
        s += e;
        cv = fmaf(e, vk, cv);
    }
    conv[(size_t)bn * CC + c] = (s > 0.0f) ? (cv / s) : 0.0f;
}

// ---------------------------------------------------------------- residual + LN
// out = LN(out + delta); one wave per row (C=256 -> 4 floats/lane).
__global__ __launch_bounds__(256) void add_ln_k(float* __restrict__ out,
                                                const float* __restrict__ del,
                                                const float* __restrict__ g,
                                                const float* __restrict__ bt) {
    const int row  = blockIdx.x * 4 + (threadIdx.x >> 6);
    const int lane = threadIdx.x & 63;
    const size_t base = (size_t)row * CC + lane * 4;
    float4 x = *reinterpret_cast<const float4*>(&out[base]);
    float4 d = *reinterpret_cast<const float4*>(&del[base]);
    float v0 = x.x + d.x, v1 = x.y + d.y, v2 = x.z + d.z, v3 = x.w + d.w;

    float s = v0 + v1 + v2 + v3;
#pragma unroll
    for (int o = 32; o > 0; o >>= 1) s += __shfl_xor(s, o);
    const float mu = s * (1.0f / 256.0f);
    const float t0 = v0 - mu, t1 = v1 - mu, t2 = v2 - mu, t3 = v3 - mu;
    float q = t0 * t0 + t1 * t1 + t2 * t2 + t3 * t3;
#pragma unroll
    for (int o = 32; o > 0; o >>= 1) q += __shfl_xor(q, o);
    const float rstd = rsqrtf(q * (1.0f / 256.0f) + 1e-5f);

    float4 gg = *reinterpret_cast<const float4*>(&g[lane * 4]);
    float4 bb = *reinterpret_cast<const float4*>(&bt[lane * 4]);
    float4 y;
    y.x = t0 * rstd * gg.x + bb.x;
    y.y = t1 * rstd * gg.y + bb.y;
    y.z = t2 * rstd * gg.z + bb.z;
    y.w = t3 * rstd * gg.w + bb.w;
    *reinterpret_cast<float4*>(&out[base]) = y;
}

// ---------------------------------------------------------------- launch
extern "C" void kernel_launch(void* const* d_in, const int* in_sizes, int n_in,
                              void* d_out, int out_size, void* d_ws, size_t ws_size,
                              hipStream_t stream) {
    const float* q_xyz   = (const float*)d_in[0];
    const float* q_feat  = (const float*)d_in[1];
    const float* kv_xyz  = (const float*)d_in[2];
    const float* kv_feat = (const float*)d_in[3];
    const float* W_src   = (const float*)d_in[4];
    const float* W_dst   = (const float*)d_in[5];
    const float* W_lin   = (const float*)d_in[6];
    const float* W_attn  = (const float*)d_in[7];
    const float* b_attn  = (const float*)d_in[8];
    const float* W1      = (const float*)d_in[9];
    const float* b1      = (const float*)d_in[10];
    const float* W2      = (const float*)d_in[11];
    const float* b2      = (const float*)d_in[12];
    const float* ln1_g   = (const float*)d_in[13];
    const float* ln1_b   = (const float*)d_in[14];
    const float* ln2_g   = (const float*)d_in[15];
    const float* ln2_b   = (const float*)d_in[16];

    float* out = (float*)d_out;
    char* wsb = (char*)d_ws;
    const size_t MB = (size_t)1 << 20;
    int*   idxb  = (int*)(wsb);               // 1 MB
    float* validb = (float*)(wsb + 1 * MB);   // 1 MB
    float* a_src = (float*)(wsb + 2 * MB);    // 16 MB
    float* a_dst = (float*)(wsb + 18 * MB);   // 16 MB
    float* vbuf  = (float*)(wsb + 34 * MB);   // 16 MB
    float* convb = (float*)(wsb + 50 * MB);   // 16 MB (also W2-out tmp)
    float* hbuf  = (float*)(wsb + 66 * MB);   // 64 MB

    const int M = BB * NN;                    // 16384 (== B*L as well)

    // out = q_feat
    copy_k<<<M * CC / (256 * 4), 256, 0, stream>>>(q_feat, out);
    // neighbor search
    knn_k<<<BB * (NN / 256), 256, 0, stream>>>(q_xyz, kv_xyz, idxb, validb);

    for (int i = 0; i < NL; ++i) {
        const float* Wsrc = W_src + (size_t)i * CC * CC;
        const float* Wdst = W_dst + (size_t)i * CC * CC;
        const float* Wlin = W_lin + (size_t)i * CC * CC;
        const float* Wat  = W_attn + (size_t)i * CC * CC;
        const float* bat  = b_attn + (size_t)i * CC;
        const float* W1p  = W1 + (size_t)i * CC * (CC * FF);
        const float* b1p  = b1 + (size_t)i * (CC * FF);
        const float* W2p  = W2 + (size_t)i * (CC * FF) * CC;
        const float* b2p  = b2 + (size_t)i * CC;

        gemm_k<0><<<dim3(CC / 128, M / 128), 256, 0, stream>>>(
            kv_feat, Wsrc, nullptr, a_src, M, CC, CC);
        gemm_k<0><<<dim3(CC / 128, M / 128), 256, 0, stream>>>(
            out, Wdst, nullptr, a_dst, M, CC, CC);
        gemm_k<0><<<dim3(CC / 128, M / 128), 256, 0, stream>>>(
            kv_feat, Wlin, nullptr, vbuf, M, CC, CC);

        attn_k<<<BB * NN, 256, 0, stream>>>(a_dst, a_src, vbuf, idxb, validb,
                                            Wat, bat, convb);
        add_ln_k<<<M / 4, 256, 0, stream>>>(out, convb,
                                            ln1_g + (size_t)i * CC, ln1_b + (size_t)i * CC);

        gemm_k<1><<<dim3(CC * FF / 128, M / 128), 256, 0, stream>>>(
            out, W1p, b1p, hbuf, M, CC * FF, CC);
        gemm_k<0><<<dim3(CC / 128, M / 128), 256, 0, stream>>>(
            hbuf, W2p, b2p, convb, M, CC, CC * FF);
        add_ln_k<<<M / 4, 256, 0, stream>>>(out, convb,
                                            ln2_g + (size_t)i * CC, ln2_b + (size_t)i * CC);
    }
    (void)in_sizes; (void)n_in; (void)out_size; (void)ws_size;
}

// Round 3
// 940.482 us; speedup vs baseline: 2.6541x; 2.6541x over previous
//
#include <hip/hip_runtime.h>
#include <math.h>

#define BB 8
#define NN 2048
#define LL 2048
#define CC 256
#define KK 16
#define NL 2
#define FF 4

typedef __attribute__((ext_vector_type(8))) short short8v;
typedef __attribute__((ext_vector_type(4))) float f32x4;

__device__ __forceinline__ short f2b(float f) {
    unsigned u = __float_as_uint(f);
    u += 0x7FFFu + ((u >> 16) & 1u);
    return (short)(u >> 16);
}
__device__ __forceinline__ float b2f(short s) {
    return __uint_as_float(((unsigned)(unsigned short)s) << 16);
}

// ---------------------------------------------------------------- copy / convert
__global__ __launch_bounds__(256) void copy_k(const float* __restrict__ src,
                                              float* __restrict__ dst) {
    size_t i = (size_t)blockIdx.x * 256 + threadIdx.x;
    reinterpret_cast<float4*>(dst)[i] = reinterpret_cast<const float4*>(src)[i];
}

__global__ __launch_bounds__(256) void f2b_k(const float* __restrict__ in,
                                             short* __restrict__ out) {
    size_t i = ((size_t)blockIdx.x * 256 + threadIdx.x) * 4;
    float4 v = *reinterpret_cast<const float4*>(in + i);
    short o[4] = {f2b(v.x), f2b(v.y), f2b(v.z), f2b(v.w)};
    *reinterpret_cast<int2*>(out + i) = *reinterpret_cast<int2*>(o);
}

// W [K][N] fp32 -> Wt [N][K] bf16
__global__ __launch_bounds__(256) void tconv_k(const float* __restrict__ W,
                                               short* __restrict__ Wt,
                                               int K, int N) {
    __shared__ float tile[32][33];
    const int n0 = blockIdx.x * 32, k0 = blockIdx.y * 32;
    const int tx = threadIdx.x & 31, ty = threadIdx.x >> 5;
#pragma unroll
    for (int r = 0; r < 32; r += 8)
        tile[ty + r][tx] = W[(size_t)(k0 + ty + r) * N + n0 + tx];
    __syncthreads();
#pragma unroll
    for (int r = 0; r < 32; r += 8)
        Wt[(size_t)(n0 + ty + r) * K + k0 + tx] = f2b(tile[tx][ty + r]);
}

// ---------------------------------------------------------------- knn
__global__ __launch_bounds__(256) void knn_k(const float* __restrict__ qxyz,
                                             const float* __restrict__ kvxyz,
                                             int* __restrict__ idx,
                                             float* __restrict__ valid) {
    __shared__ float s[LL * 3];
    const int b = blockIdx.x >> 3;
    const int n = ((blockIdx.x & 7) << 8) + threadIdx.x;
    const float* kb = kvxyz + (size_t)b * LL * 3;
    for (int t = threadIdx.x; t < LL * 3; t += 256) s[t] = kb[t];
    __syncthreads();

    const size_t q = (size_t)(b * NN + n) * 3;
    const float qx = qxyz[q], qy = qxyz[q + 1], qz = qxyz[q + 2];

    float bd[KK];
    int   bi[KK];
#pragma unroll
    for (int k = 0; k < KK; ++k) { bd[k] = 3e38f; bi[k] = 0; }
    float worst = 3e38f; int wslot = 0;

    for (int j = 0; j < LL; ++j) {
        float dx = qx - s[3 * j];
        float dy = qy - s[3 * j + 1];
        float dz = qz - s[3 * j + 2];
        float d2 = dx * dx + dy * dy + dz * dz;
        if (d2 < worst) {
            bd[wslot] = d2; bi[wslot] = j;
            worst = bd[0]; wslot = 0;
#pragma unroll
            for (int k = 1; k < KK; ++k)
                if (bd[k] > worst) { worst = bd[k]; wslot = k; }
        }
    }
    const float rad2 = (float)(0.12 * 0.12);
    const size_t o = (size_t)(b * NN + n) * KK;
#pragma unroll
    for (int k = 0; k < KK; ++k) {
        idx[o + k]   = bi[k];
        valid[o + k] = (bd[k] <= rad2) ? 1.0f : 0.0f;
    }
}

// ---------------------------------------------------------------- bf16 MFMA GEMM
// C[M,N] = act(A[M,Kd] @ Bt[N,Kd]^T + bias). 128x128 tile, 4 waves (2x2),
// each wave 64x64 = 4x4 fragments of mfma_f32_16x16x32_bf16.
template <int ACT, int OBF>
__global__ __launch_bounds__(256) void mm_k(const short* __restrict__ A,
                                            const short* __restrict__ Bt,
                                            const float* __restrict__ bias,
                                            void* __restrict__ Cout,
                                            int M, int N, int Kd) {
    __shared__ __align__(16) short As[128 * 32];
    __shared__ __align__(16) short Bs[128 * 32];
    const int t = threadIdx.x;
    const int lane = t & 63;
    const int wv = t >> 6;
    const int wr = wv >> 1, wc = wv & 1;
    const int lrow = lane & 15;
    const int kc = lane >> 4;
    const int row0 = blockIdx.y * 128;
    const int col0 = blockIdx.x * 128;

    f32x4 acc[4][4];
#pragma unroll
    for (int m = 0; m < 4; ++m)
#pragma unroll
        for (int n = 0; n < 4; ++n) acc[m][n] = f32x4{0.f, 0.f, 0.f, 0.f};

    const int r0 = t >> 2, cch = t & 3;
    const int r1 = r0 + 64;

    for (int k0 = 0; k0 < Kd; k0 += 32) {
        __syncthreads();
        {
            int4 va = *(const int4*)(A  + (size_t)(row0 + r0) * Kd + k0 + cch * 8);
            int4 vb = *(const int4*)(Bt + (size_t)(col0 + r0) * Kd + k0 + cch * 8);
            *(int4*)(As + r0 * 32 + ((cch ^ ((r0 >> 1) & 3)) * 8)) = va;
            *(int4*)(Bs + r0 * 32 + ((cch ^ ((r0 >> 1) & 3)) * 8)) = vb;
            int4 va2 = *(const int4*)(A  + (size_t)(row0 + r1) * Kd + k0 + cch * 8);
            int4 vb2 = *(const int4*)(Bt + (size_t)(col0 + r1) * Kd + k0 + cch * 8);
            *(int4*)(As + r1 * 32 + ((cch ^ ((r1 >> 1) & 3)) * 8)) = va2;
            *(int4*)(Bs + r1 * 32 + ((cch ^ ((r1 >> 1) & 3)) * 8)) = vb2;
        }
        __syncthreads();
        short8v af[4], bf[4];
#pragma unroll
        for (int m = 0; m < 4; ++m) {
            const int ar = wr * 64 + m * 16 + lrow;
            af[m] = *(const short8v*)(As + ar * 32 + ((kc ^ ((ar >> 1) & 3)) * 8));
        }
#pragma unroll
        for (int n = 0; n < 4; ++n) {
            const int br = wc * 64 + n * 16 + lrow;
            bf[n] = *(const short8v*)(Bs + br * 32 + ((kc ^ ((br >> 1) & 3)) * 8));
        }
#pragma unroll
        for (int m = 0; m < 4; ++m)
#pragma unroll
            for (int n = 0; n < 4; ++n)
                acc[m][n] = __builtin_amdgcn_mfma_f32_16x16x32_bf16(
                    af[m], bf[n], acc[m][n], 0, 0, 0);
    }

    float bcol[4];
#pragma unroll
    for (int n = 0; n < 4; ++n)
        bcol[n] = bias ? bias[col0 + wc * 64 + n * 16 + lrow] : 0.f;

#pragma unroll
    for (int m = 0; m < 4; ++m) {
#pragma unroll
        for (int n = 0; n < 4; ++n) {
            const int col = col0 + wc * 64 + n * 16 + lrow;
#pragma unroll
            for (int r = 0; r < 4; ++r) {
                const int row = row0 + wr * 64 + m * 16 + kc * 4 + r;
                float v = acc[m][n][r] + bcol[n];
                if (ACT == 1) v = 0.5f * v * (1.0f + erff(v * 0.70710678118654752f));
                if (OBF) ((short*)Cout)[(size_t)row * N + col] = f2b(v);
                else     ((float*)Cout)[(size_t)row * N + col] = v;
            }
        }
    }
}

// ---------------------------------------------------------------- fused attention (MFMA)
// Block = 8 queries (128 diff rows) x 128 channels. logits = diff @ W_attn
// via MFMA; per-channel softmax over K=16 = one 16x16 C-fragment's rows
// (in-thread over 4 regs + shfl_xor 16/32); conv vs LDS-staged gathered V.
__global__ __launch_bounds__(256) void attn_k(
    const short* __restrict__ adst, const short* __restrict__ asrc,
    const short* __restrict__ vf, const int* __restrict__ idx,
    const float* __restrict__ valid, const short* __restrict__ Wat_t,
    const float* __restrict__ bat, float* __restrict__ conv) {
    __shared__ __align__(16) short smem[128 * 136];  // vt; first 8192 = As|Bs
    __shared__ int   sidx[128];
    __shared__ float sval[128];
    short* As = smem;
    short* Bs = smem + 4096;

    const int t = threadIdx.x;
    const int lane = t & 63;
    const int wv = t >> 6, wr = wv >> 1, wc = wv & 1;
    const int lrow = lane & 15, kc = lane >> 4;
    const int bn0 = blockIdx.y * 8;
    const int c0 = blockIdx.x * 128;
    const size_t boff = (size_t)(bn0 >> 11) * LL;   // batch row offset into [B*L][C]

    if (t < 128) {
        sidx[t] = idx[(size_t)bn0 * KK + t];
        sval[t] = valid[(size_t)bn0 * KK + t];
    }

    f32x4 acc[4][4];
#pragma unroll
    for (int m = 0; m < 4; ++m)
#pragma unroll
        for (int n = 0; n < 4; ++n) acc[m][n] = f32x4{0.f, 0.f, 0.f, 0.f};

    __syncthreads();

    const int r0 = t >> 2, cch = t & 3;
    const int r1 = r0 + 64;

    for (int k0 = 0; k0 < CC; k0 += 32) {
        __syncthreads();
        {
            // diff rows r0, r1: a_dst[bn] - a_src[b*L + idx]
            int bn = bn0 + (r0 >> 4);
            int sj = sidx[r0];
            int4 dd = *(const int4*)(adst + (size_t)bn * CC + k0 + cch * 8);
            int4 ss = *(const int4*)(asrc + (boff + sj) * CC + k0 + cch * 8);
            const short* dp = (const short*)&dd;
            const short* sp = (const short*)&ss;
            short o[8];
#pragma unroll
            for (int e = 0; e < 8; ++e) o[e] = f2b(b2f(dp[e]) - b2f(sp[e]));
            *(int4*)(As + r0 * 32 + ((cch ^ ((r0 >> 1) & 3)) * 8)) = *(int4*)o;

            int bn2 = bn0 + (r1 >> 4);
            int sj2 = sidx[r1];
            int4 dd2 = *(const int4*)(adst + (size_t)bn2 * CC + k0 + cch * 8);
            int4 ss2 = *(const int4*)(asrc + (boff + sj2) * CC + k0 + cch * 8);
            const short* dp2 = (const short*)&dd2;
            const short* sp2 = (const short*)&ss2;
            short o2[8];
#pragma unroll
            for (int e = 0; e < 8; ++e) o2[e] = f2b(b2f(dp2[e]) - b2f(sp2[e]));
            *(int4*)(As + r1 * 32 + ((cch ^ ((r1 >> 1) & 3)) * 8)) = *(int4*)o2;

            // W_attn^T tile
            int4 vb = *(const int4*)(Wat_t + (size_t)(c0 + r0) * CC + k0 + cch * 8);
            *(int4*)(Bs + r0 * 32 + ((cch ^ ((r0 >> 1) & 3)) * 8)) = vb;
            int4 vb2 = *(const int4*)(Wat_t + (size_t)(c0 + r1) * CC + k0 + cch * 8);
            *(int4*)(Bs + r1 * 32 + ((cch ^ ((r1 >> 1) & 3)) * 8)) = vb2;
        }
        __syncthreads();
        short8v af[4], bf[4];
#pragma unroll
        for (int m = 0; m < 4; ++m) {
            const int ar = wr * 64 + m * 16 + lrow;
            af[m] = *(const short8v*)(As + ar * 32 + ((kc ^ ((ar >> 1) & 3)) * 8));
        }
#pragma unroll
        for (int n = 0; n < 4; ++n) {
            const int br = wc * 64 + n * 16 + lrow;
            bf[n] = *(const short8v*)(Bs + br * 32 + ((kc ^ ((br >> 1) & 3)) * 8));
        }
#pragma unroll
        for (int m = 0; m < 4; ++m)
#pragma unroll
            for (int n = 0; n < 4; ++n)
                acc[m][n] = __builtin_amdgcn_mfma_f32_16x16x32_bf16(
                    af[m], bf[n], acc[m][n], 0, 0, 0);
    }

    // stage gathered V tile [128 rows][128 cols] bf16, rows padded to 136
    __syncthreads();
#pragma unroll
    for (int p = 0; p < 8; ++p) {
        const int q = t + 256 * p;
        const int row = q >> 4, ch = q & 15;
        const int sj = sidx[row];
        int4 vv = *(const int4*)(vf + (boff + sj) * CC + c0 + ch * 8);
        *(int4*)(smem + row * 136 + ch * 8) = vv;
    }
    __syncthreads();

    float bcol[4];
#pragma unroll
    for (int n = 0; n < 4; ++n)
        bcol[n] = bat[c0 + wc * 64 + n * 16 + lrow];

#pragma unroll
    for (int m = 0; m < 4; ++m) {
        const int ql = wr * 4 + m;
#pragma unroll
        for (int n = 0; n < 4; ++n) {
            const int ctile = wc * 64 + n * 16 + lrow;
            float l[4];
#pragma unroll
            for (int r = 0; r < 4; ++r) {
                const int k = kc * 4 + r;
                float a = fmaxf(acc[m][n][r] + bcol[n], 0.f);
                l[r] = (sval[ql * 16 + k] > 0.5f) ? a : -1e9f;
            }
            float mx = fmaxf(fmaxf(l[0], l[1]), fmaxf(l[2], l[3]));
            mx = fmaxf(mx, __shfl_xor(mx, 16));
            mx = fmaxf(mx, __shfl_xor(mx, 32));
            float s = 0.f, num = 0.f;
#pragma unroll
            for (int r = 0; r < 4; ++r) {
                const int k = kc * 4 + r;
                const float e = (l[r] > -5e8f) ? __expf(l[r] - mx) : 0.f;
                s += e;
                num = fmaf(e, b2f(smem[(ql * 16 + k) * 136 + ctile]), num);
            }
            s += __shfl_xor(s, 16);  s += __shfl_xor(s, 32);
            num += __shfl_xor(num, 16); num += __shfl_xor(num, 32);
            if (kc == 0)
                conv[(size_t)(bn0 + ql) * CC + c0 + ctile] = (s > 0.f) ? num / s : 0.f;
        }
    }
}

// ---------------------------------------------------------------- residual + LN (+ bf16 mirror)
__global__ __launch_bounds__(256) void add_ln_k(float* __restrict__ out,
                                                const float* __restrict__ del,
                                                const float* __restrict__ g,
                                                const float* __restrict__ bt,
                                                short* __restrict__ ob) {
    const int row  = blockIdx.x * 4 + (threadIdx.x >> 6);
    const int lane = threadIdx.x & 63;
    const size_t base = (size_t)row * CC + lane * 4;
    float4 x = *reinterpret_cast<const float4*>(&out[base]);
    float4 d = *reinterpret_cast<const float4*>(&del[base]);
    float v0 = x.x + d.x, v1 = x.y + d.y, v2 = x.z + d.z, v3 = x.w + d.w;

    float s = v0 + v1 + v2 + v3;
#pragma unroll
    for (int o = 32; o > 0; o >>= 1) s += __shfl_xor(s, o);
    const float mu = s * (1.0f / 256.0f);
    const float t0 = v0 - mu, t1 = v1 - mu, t2 = v2 - mu, t3 = v3 - mu;
    float q = t0 * t0 + t1 * t1 + t2 * t2 + t3 * t3;
#pragma unroll
    for (int o = 32; o > 0; o >>= 1) q += __shfl_xor(q, o);
    const float rstd = rsqrtf(q * (1.0f / 256.0f) + 1e-5f);

    float4 gg = *reinterpret_cast<const float4*>(&g[lane * 4]);
    float4 bb = *reinterpret_cast<const float4*>(&bt[lane * 4]);
    float4 y;
    y.x = t0 * rstd * gg.x + bb.x;
    y.y = t1 * rstd * gg.y + bb.y;
    y.z = t2 * rstd * gg.z + bb.z;
    y.w = t3 * rstd * gg.w + bb.w;
    *reinterpret_cast<float4*>(&out[base]) = y;
    short o4[4] = {f2b(y.x), f2b(y.y), f2b(y.z), f2b(y.w)};
    *reinterpret_cast<int2*>(ob + base) = *reinterpret_cast<int2*>(o4);
}

// ---------------------------------------------------------------- launch
extern "C" void kernel_launch(void* const* d_in, const int* in_sizes, int n_in,
                              void* d_out, int out_size, void* d_ws, size_t ws_size,
                              hipStream_t stream) {
    const float* q_xyz   = (const float*)d_in[0];
    const float* q_feat  = (const float*)d_in[1];
    const float* kv_xyz  = (const float*)d_in[2];
    const float* kv_feat = (const float*)d_in[3];
    const float* W_src   = (const float*)d_in[4];
    const float* W_dst   = (const float*)d_in[5];
    const float* W_lin   = (const float*)d_in[6];
    const float* W_attn  = (const float*)d_in[7];
    const float* b_attn  = (const float*)d_in[8];
    const float* W1      = (const float*)d_in[9];
    const float* b1      = (const float*)d_in[10];
    const float* W2      = (const float*)d_in[11];
    const float* b2      = (const float*)d_in[12];
    const float* ln1_g   = (const float*)d_in[13];
    const float* ln1_b   = (const float*)d_in[14];
    const float* ln2_g   = (const float*)d_in[15];
    const float* ln2_b   = (const float*)d_in[16];

    float* out = (float*)d_out;
    char* wsb = (char*)d_ws;
    const size_t MB = (size_t)1 << 20;
    int*   idxb   = (int*)(wsb);                 // 1 MB
    float* validb = (float*)(wsb + 1 * MB);      // 1 MB
    short* kvf16  = (short*)(wsb + 2 * MB);      // 8 MB
    short* outb16 = (short*)(wsb + 10 * MB);     // 8 MB
    short* asrc16 = (short*)(wsb + 18 * MB);     // 8 MB
    short* adst16 = (short*)(wsb + 26 * MB);     // 8 MB
    short* v16    = (short*)(wsb + 34 * MB);     // 8 MB
    short* h16    = (short*)(wsb + 42 * MB);     // 32 MB
    float* convb  = (float*)(wsb + 74 * MB);     // 16 MB
    short* WsrcT  = (short*)(wsb + 90 * MB);     // 256 KB  (NL x 256x256 bf16)
    short* WdstT  = (short*)(wsb + 90 * MB + 256 * 1024);
    short* WlinT  = (short*)(wsb + 90 * MB + 512 * 1024);
    short* WatT   = (short*)(wsb + 90 * MB + 768 * 1024);
    short* W1T    = (short*)(wsb + 91 * MB);     // 1 MB (NL x 1024x256 bf16)
    short* W2T    = (short*)(wsb + 92 * MB);     // 1 MB (NL x 256x1024 bf16)

    const int M = BB * NN;                       // 16384

    // init + conversions
    copy_k<<<M * CC / (256 * 4), 256, 0, stream>>>(q_feat, out);
    f2b_k<<<M * CC / (256 * 4), 256, 0, stream>>>(q_feat, outb16);
    f2b_k<<<M * CC / (256 * 4), 256, 0, stream>>>(kv_feat, kvf16);
    knn_k<<<BB * (NN / 256), 256, 0, stream>>>(q_xyz, kv_xyz, idxb, validb);

    for (int i = 0; i < NL; ++i) {
        const size_t oC = (size_t)i * CC * CC;
        const size_t oF = (size_t)i * CC * CC * FF;
        tconv_k<<<dim3(8, 8),  256, 0, stream>>>(W_src + oC,  WsrcT + oC, CC, CC);
        tconv_k<<<dim3(8, 8),  256, 0, stream>>>(W_dst + oC,  WdstT + oC, CC, CC);
        tconv_k<<<dim3(8, 8),  256, 0, stream>>>(W_lin + oC,  WlinT + oC, CC, CC);
        tconv_k<<<dim3(8, 8),  256, 0, stream>>>(W_attn + oC, WatT  + oC, CC, CC);
        tconv_k<<<dim3(32, 8), 256, 0, stream>>>(W1 + oF, W1T + oF, CC, CC * FF);
        tconv_k<<<dim3(8, 32), 256, 0, stream>>>(W2 + oF, W2T + oF, CC * FF, CC);
    }

    for (int i = 0; i < NL; ++i) {
        const size_t oC = (size_t)i * CC * CC;
        const size_t oF = (size_t)i * CC * CC * FF;
        const float* bat = b_attn + (size_t)i * CC;
        const float* b1p = b1 + (size_t)i * CC * FF;
        const float* b2p = b2 + (size_t)i * CC;

        mm_k<0, 1><<<dim3(2, 128), 256, 0, stream>>>(kvf16,  WsrcT + oC, nullptr, asrc16, M, CC, CC);
        mm_k<0, 1><<<dim3(2, 128), 256, 0, stream>>>(outb16, WdstT + oC, nullptr, adst16, M, CC, CC);
        mm_k<0, 1><<<dim3(2, 128), 256, 0, stream>>>(kvf16,  WlinT + oC, nullptr, v16,    M, CC, CC);

        attn_k<<<dim3(2, M / 8), 256, 0, stream>>>(adst16, asrc16, v16, idxb, validb,
                                                   WatT + oC, bat, convb);
        add_ln_k<<<M / 4, 256, 0, stream>>>(out, convb,
                                            ln1_g + (size_t)i * CC, ln1_b + (size_t)i * CC, outb16);

        mm_k<1, 1><<<dim3(8, 128), 256, 0, stream>>>(outb16, W1T + oF, b1p, h16, M, CC * FF, CC);
        mm_k<0, 0><<<dim3(2, 128), 256, 0, stream>>>(h16, W2T + oF, b2p, convb, M, CC, CC * FF);
        add_ln_k<<<M / 4, 256, 0, stream>>>(out, convb,
                                            ln2_g + (size_t)i * CC, ln2_b + (size_t)i * CC, outb16);
    }
    (void)in_sizes; (void)n_in; (void)out_size; (void)ws_size;
}

// Round 4
// 623.425 us; speedup vs baseline: 4.0039x; 1.5086x over previous
//
#include <hip/hip_runtime.h>
#include <math.h>

#define BB 8
#define NN 2048
#define LL 2048
#define CC 256
#define KK 16
#define NL 2
#define FF 4

typedef __attribute__((ext_vector_type(8))) short short8v;
typedef __attribute__((ext_vector_type(4))) float f32x4;

__device__ __forceinline__ short f2b(float f) {
    unsigned u = __float_as_uint(f);
    u += 0x7FFFu + ((u >> 16) & 1u);
    return (short)(u >> 16);
}
__device__ __forceinline__ float b2f(short s) {
    return __uint_as_float(((unsigned)(unsigned short)s) << 16);
}

// ---------------------------------------------------------------- init: out=q_feat (f32 + bf16 mirror)
__global__ __launch_bounds__(256) void init_k(const float* __restrict__ src,
                                              float* __restrict__ dst,
                                              short* __restrict__ dstb) {
    size_t i = ((size_t)blockIdx.x * 256 + threadIdx.x) * 4;
    float4 v = *reinterpret_cast<const float4*>(src + i);
    *reinterpret_cast<float4*>(dst + i) = v;
    short o[4] = {f2b(v.x), f2b(v.y), f2b(v.z), f2b(v.w)};
    *reinterpret_cast<int2*>(dstb + i) = *reinterpret_cast<int2*>(o);
}

__global__ __launch_bounds__(256) void f2b_k(const float* __restrict__ in,
                                             short* __restrict__ out) {
    size_t i = ((size_t)blockIdx.x * 256 + threadIdx.x) * 4;
    float4 v = *reinterpret_cast<const float4*>(in + i);
    short o[4] = {f2b(v.x), f2b(v.y), f2b(v.z), f2b(v.w)};
    *reinterpret_cast<int2*>(out + i) = *reinterpret_cast<int2*>(o);
}

// W [K][N] fp32 -> Wt [N][K] bf16
__global__ __launch_bounds__(256) void tconv_k(const float* __restrict__ W,
                                               short* __restrict__ Wt,
                                               int K, int N) {
    __shared__ float tile[32][33];
    const int n0 = blockIdx.x * 32, k0 = blockIdx.y * 32;
    const int tx = threadIdx.x & 31, ty = threadIdx.x >> 5;
#pragma unroll
    for (int r = 0; r < 32; r += 8)
        tile[ty + r][tx] = W[(size_t)(k0 + ty + r) * N + n0 + tx];
    __syncthreads();
#pragma unroll
    for (int r = 0; r < 32; r += 8)
        Wt[(size_t)(n0 + ty + r) * K + k0 + tx] = f2b(tile[tx][ty + r]);
}

// ---------------------------------------------------------------- knn (cooperative: 4 threads/query)
// Block = 256 thr = 64 queries; each thread scans 512 points (stride-4 set),
// keeps local top-16; leader merges 4 lists. Grid = B * N/64 = 256 blocks.
__global__ __launch_bounds__(256) void knn_k(const float* __restrict__ qxyz,
                                             const float* __restrict__ kvxyz,
                                             int* __restrict__ idx,
                                             float* __restrict__ valid) {
    __shared__ float4 sxyz[LL];          // 32 KB
    __shared__ float  cd[64][65];        // candidates (pad 65 breaks bank align)
    __shared__ int    ci[64][65];

    const int t   = threadIdx.x;
    const int q   = t >> 2;              // local query 0..63
    const int sub = t & 3;
    const int b   = blockIdx.x >> 5;
    const int n   = ((blockIdx.x & 31) << 6) + q;

    const float* kb = kvxyz + (size_t)b * LL * 3;
    for (int p = t; p < LL; p += 256)
        sxyz[p] = make_float4(kb[3 * p], kb[3 * p + 1], kb[3 * p + 2], 0.f);
    __syncthreads();

    const size_t qo = (size_t)(b * NN + n) * 3;
    const float qx = qxyz[qo], qy = qxyz[qo + 1], qz = qxyz[qo + 2];

    float bd[KK];
    int   bi[KK];
#pragma unroll
    for (int k = 0; k < KK; ++k) { bd[k] = 3e38f; bi[k] = 0; }
    float worst = 3e38f; int ws = 0;

#define RESCAN()                                                 \
    do { worst = bd[0]; ws = 0;                                  \
         _Pragma("unroll")                                       \
         for (int k = 1; k < KK; ++k)                            \
             if (bd[k] > worst) { worst = bd[k]; ws = k; }       \
    } while (0)

    for (int j = sub; j < LL; j += 16) {
        float4 p0 = sxyz[j];
        float4 p1 = sxyz[j + 4];
        float4 p2 = sxyz[j + 8];
        float4 p3 = sxyz[j + 12];
        float x0 = qx - p0.x, y0 = qy - p0.y, z0 = qz - p0.z;
        float x1 = qx - p1.x, y1 = qy - p1.y, z1 = qz - p1.z;
        float x2 = qx - p2.x, y2 = qy - p2.y, z2 = qz - p2.z;
        float x3 = qx - p3.x, y3 = qy - p3.y, z3 = qz - p3.z;
        float d0 = fmaf(x0, x0, fmaf(y0, y0, z0 * z0));
        float d1 = fmaf(x1, x1, fmaf(y1, y1, z1 * z1));
        float d2 = fmaf(x2, x2, fmaf(y2, y2, z2 * z2));
        float d3 = fmaf(x3, x3, fmaf(y3, y3, z3 * z3));
        float mn = fminf(fminf(d0, d1), fminf(d2, d3));
        if (mn < worst) {
            if (d0 < worst) { bd[ws] = d0; bi[ws] = j;      RESCAN(); }
            if (d1 < worst) { bd[ws] = d1; bi[ws] = j + 4;  RESCAN(); }
            if (d2 < worst) { bd[ws] = d2; bi[ws] = j + 8;  RESCAN(); }
            if (d3 < worst) { bd[ws] = d3; bi[ws] = j + 12; RESCAN(); }
        }
    }

#pragma unroll
    for (int k = 0; k < KK; ++k) {
        cd[q][sub * KK + k] = bd[k];
        ci[q][sub * KK + k] = bi[k];
    }
    __syncthreads();

    if (sub == 0) {
        for (int j = KK; j < 64; ++j) {
            float d2 = cd[q][j];
            if (d2 < worst) { bd[ws] = d2; bi[ws] = ci[q][j]; RESCAN(); }
        }
        const float rad2 = (float)(0.12 * 0.12);
        const size_t o = (size_t)(b * NN + n) * KK;
#pragma unroll
        for (int k = 0; k < KK; ++k) {
            idx[o + k]   = bi[k];
            valid[o + k] = (bd[k] <= rad2) ? 1.0f : 0.0f;
        }
    }
#undef RESCAN
}

// ---------------------------------------------------------------- bf16 MFMA GEMM
// C[M,N] = act(A[M,Kd] @ Bt[N,Kd]^T + bias). 128x128 tile, 4 waves (2x2),
// each wave 64x64 = 4x4 fragments of mfma_f32_16x16x32_bf16.
template <int ACT, int OBF>
__global__ __launch_bounds__(256) void mm_k(const short* __restrict__ A,
                                            const short* __restrict__ Bt,
                                            const float* __restrict__ bias,
                                            void* __restrict__ Cout,
                                            int M, int N, int Kd) {
    __shared__ __align__(16) short As[128 * 32];
    __shared__ __align__(16) short Bs[128 * 32];
    const int t = threadIdx.x;
    const int lane = t & 63;
    const int wv = t >> 6;
    const int wr = wv >> 1, wc = wv & 1;
    const int lrow = lane & 15;
    const int kc = lane >> 4;
    const int row0 = blockIdx.y * 128;
    const int col0 = blockIdx.x * 128;

    f32x4 acc[4][4];
#pragma unroll
    for (int m = 0; m < 4; ++m)
#pragma unroll
        for (int n = 0; n < 4; ++n) acc[m][n] = f32x4{0.f, 0.f, 0.f, 0.f};

    const int r0 = t >> 2, cch = t & 3;
    const int r1 = r0 + 64;

    for (int k0 = 0; k0 < Kd; k0 += 32) {
        __syncthreads();
        {
            int4 va = *(const int4*)(A  + (size_t)(row0 + r0) * Kd + k0 + cch * 8);
            int4 vb = *(const int4*)(Bt + (size_t)(col0 + r0) * Kd + k0 + cch * 8);
            *(int4*)(As + r0 * 32 + ((cch ^ ((r0 >> 1) & 3)) * 8)) = va;
            *(int4*)(Bs + r0 * 32 + ((cch ^ ((r0 >> 1) & 3)) * 8)) = vb;
            int4 va2 = *(const int4*)(A  + (size_t)(row0 + r1) * Kd + k0 + cch * 8);
            int4 vb2 = *(const int4*)(Bt + (size_t)(col0 + r1) * Kd + k0 + cch * 8);
            *(int4*)(As + r1 * 32 + ((cch ^ ((r1 >> 1) & 3)) * 8)) = va2;
            *(int4*)(Bs + r1 * 32 + ((cch ^ ((r1 >> 1) & 3)) * 8)) = vb2;
        }
        __syncthreads();
        short8v af[4], bf[4];
#pragma unroll
        for (int m = 0; m < 4; ++m) {
            const int ar = wr * 64 + m * 16 + lrow;
            af[m] = *(const short8v*)(As + ar * 32 + ((kc ^ ((ar >> 1) & 3)) * 8));
        }
#pragma unroll
        for (int n = 0; n < 4; ++n) {
            const int br = wc * 64 + n * 16 + lrow;
            bf[n] = *(const short8v*)(Bs + br * 32 + ((kc ^ ((br >> 1) & 3)) * 8));
        }
#pragma unroll
        for (int m = 0; m < 4; ++m)
#pragma unroll
            for (int n = 0; n < 4; ++n)
                acc[m][n] = __builtin_amdgcn_mfma_f32_16x16x32_bf16(
                    af[m], bf[n], acc[m][n], 0, 0, 0);
    }

    float bcol[4];
#pragma unroll
    for (int n = 0; n < 4; ++n)
        bcol[n] = bias ? bias[col0 + wc * 64 + n * 16 + lrow] : 0.f;

#pragma unroll
    for (int m = 0; m < 4; ++m) {
#pragma unroll
        for (int n = 0; n < 4; ++n) {
            const int col = col0 + wc * 64 + n * 16 + lrow;
#pragma unroll
            for (int r = 0; r < 4; ++r) {
                const int row = row0 + wr * 64 + m * 16 + kc * 4 + r;
                float v = acc[m][n][r] + bcol[n];
                if (ACT == 1) v = 0.5f * v * (1.0f + erff(v * 0.70710678118654752f));
                if (OBF) ((short*)Cout)[(size_t)row * N + col] = f2b(v);
                else     ((float*)Cout)[(size_t)row * N + col] = v;
            }
        }
    }
}

// ---------------------------------------------------------------- fused attention (MFMA)
__global__ __launch_bounds__(256) void attn_k(
    const short* __restrict__ adst, const short* __restrict__ asrc,
    const short* __restrict__ vf, const int* __restrict__ idx,
    const float* __restrict__ valid, const short* __restrict__ Wat_t,
    const float* __restrict__ bat, float* __restrict__ conv) {
    __shared__ __align__(16) short smem[128 * 136];  // vt; first 8192 = As|Bs
    __shared__ int   sidx[128];
    __shared__ float sval[128];
    short* As = smem;
    short* Bs = smem + 4096;

    const int t = threadIdx.x;
    const int lane = t & 63;
    const int wv = t >> 6, wr = wv >> 1, wc = wv & 1;
    const int lrow = lane & 15, kc = lane >> 4;
    const int bn0 = blockIdx.y * 8;
    const int c0 = blockIdx.x * 128;
    const size_t boff = (size_t)(bn0 >> 11) * LL;   // batch row offset into [B*L][C]

    if (t < 128) {
        sidx[t] = idx[(size_t)bn0 * KK + t];
        sval[t] = valid[(size_t)bn0 * KK + t];
    }

    f32x4 acc[4][4];
#pragma unroll
    for (int m = 0; m < 4; ++m)
#pragma unroll
        for (int n = 0; n < 4; ++n) acc[m][n] = f32x4{0.f, 0.f, 0.f, 0.f};

    __syncthreads();

    const int r0 = t >> 2, cch = t & 3;
    const int r1 = r0 + 64;

    for (int k0 = 0; k0 < CC; k0 += 32) {
        __syncthreads();
        {
            int bn = bn0 + (r0 >> 4);
            int sj = sidx[r0];
            int4 dd = *(const int4*)(adst + (size_t)bn * CC + k0 + cch * 8);
            int4 ss = *(const int4*)(asrc + (boff + sj) * CC + k0 + cch * 8);
            const short* dp = (const short*)&dd;
            const short* sp = (const short*)&ss;
            short o[8];
#pragma unroll
            for (int e = 0; e < 8; ++e) o[e] = f2b(b2f(dp[e]) - b2f(sp[e]));
            *(int4*)(As + r0 * 32 + ((cch ^ ((r0 >> 1) & 3)) * 8)) = *(int4*)o;

            int bn2 = bn0 + (r1 >> 4);
            int sj2 = sidx[r1];
            int4 dd2 = *(const int4*)(adst + (size_t)bn2 * CC + k0 + cch * 8);
            int4 ss2 = *(const int4*)(asrc + (boff + sj2) * CC + k0 + cch * 8);
            const short* dp2 = (const short*)&dd2;
            const short* sp2 = (const short*)&ss2;
            short o2[8];
#pragma unroll
            for (int e = 0; e < 8; ++e) o2[e] = f2b(b2f(dp2[e]) - b2f(sp2[e]));
            *(int4*)(As + r1 * 32 + ((cch ^ ((r1 >> 1) & 3)) * 8)) = *(int4*)o2;

            int4 vb = *(const int4*)(Wat_t + (size_t)(c0 + r0) * CC + k0 + cch * 8);
            *(int4*)(Bs + r0 * 32 + ((cch ^ ((r0 >> 1) & 3)) * 8)) = vb;
            int4 vb2 = *(const int4*)(Wat_t + (size_t)(c0 + r1) * CC + k0 + cch * 8);
            *(int4*)(Bs + r1 * 32 + ((cch ^ ((r1 >> 1) & 3)) * 8)) = vb2;
        }
        __syncthreads();
        short8v af[4], bf[4];
#pragma unroll
        for (int m = 0; m < 4; ++m) {
            const int ar = wr * 64 + m * 16 + lrow;
            af[m] = *(const short8v*)(As + ar * 32 + ((kc ^ ((ar >> 1) & 3)) * 8));
        }
#pragma unroll
        for (int n = 0; n < 4; ++n) {
            const int br = wc * 64 + n * 16 + lrow;
            bf[n] = *(const short8v*)(Bs + br * 32 + ((kc ^ ((br >> 1) & 3)) * 8));
        }
#pragma unroll
        for (int m = 0; m < 4; ++m)
#pragma unroll
            for (int n = 0; n < 4; ++n)
                acc[m][n] = __builtin_amdgcn_mfma_f32_16x16x32_bf16(
                    af[m], bf[n], acc[m][n], 0, 0, 0);
    }

    __syncthreads();
#pragma unroll
    for (int p = 0; p < 8; ++p) {
        const int q = t + 256 * p;
        const int row = q >> 4, ch = q & 15;
        const int sj = sidx[row];
        int4 vv = *(const int4*)(vf + (boff + sj) * CC + c0 + ch * 8);
        *(int4*)(smem + row * 136 + ch * 8) = vv;
    }
    __syncthreads();

    float bcol[4];
#pragma unroll
    for (int n = 0; n < 4; ++n)
        bcol[n] = bat[c0 + wc * 64 + n * 16 + lrow];

#pragma unroll
    for (int m = 0; m < 4; ++m) {
        const int ql = wr * 4 + m;
#pragma unroll
        for (int n = 0; n < 4; ++n) {
            const int ctile = wc * 64 + n * 16 + lrow;
            float l[4];
#pragma unroll
            for (int r = 0; r < 4; ++r) {
                const int k = kc * 4 + r;
                float a = fmaxf(acc[m][n][r] + bcol[n], 0.f);
                l[r] = (sval[ql * 16 + k] > 0.5f) ? a : -1e9f;
            }
            float mx = fmaxf(fmaxf(l[0], l[1]), fmaxf(l[2], l[3]));
            mx = fmaxf(mx, __shfl_xor(mx, 16));
            mx = fmaxf(mx, __shfl_xor(mx, 32));
            float s = 0.f, num = 0.f;
#pragma unroll
            for (int r = 0; r < 4; ++r) {
                const int k = kc * 4 + r;
                const float e = (l[r] > -5e8f) ? __expf(l[r] - mx) : 0.f;
                s += e;
                num = fmaf(e, b2f(smem[(ql * 16 + k) * 136 + ctile]), num);
            }
            s += __shfl_xor(s, 16);  s += __shfl_xor(s, 32);
            num += __shfl_xor(num, 16); num += __shfl_xor(num, 32);
            if (kc == 0)
                conv[(size_t)(bn0 + ql) * CC + c0 + ctile] = (s > 0.f) ? num / s : 0.f;
        }
    }
}

// ---------------------------------------------------------------- residual + LN (+ bf16 mirror)
__global__ __launch_bounds__(256) void add_ln_k(float* __restrict__ out,
                                                const float* __restrict__ del,
                                                const float* __restrict__ g,
                                                const float* __restrict__ bt,
                                                short* __restrict__ ob) {
    const int row  = blockIdx.x * 4 + (threadIdx.x >> 6);
    const int lane = threadIdx.x & 63;
    const size_t base = (size_t)row * CC + lane * 4;
    float4 x = *reinterpret_cast<const float4*>(&out[base]);
    float4 d = *reinterpret_cast<const float4*>(&del[base]);
    float v0 = x.x + d.x, v1 = x.y + d.y, v2 = x.z + d.z, v3 = x.w + d.w;

    float s = v0 + v1 + v2 + v3;
#pragma unroll
    for (int o = 32; o > 0; o >>= 1) s += __shfl_xor(s, o);
    const float mu = s * (1.0f / 256.0f);
    const float t0 = v0 - mu, t1 = v1 - mu, t2 = v2 - mu, t3 = v3 - mu;
    float q = t0 * t0 + t1 * t1 + t2 * t2 + t3 * t3;
#pragma unroll
    for (int o = 32; o > 0; o >>= 1) q += __shfl_xor(q, o);
    const float rstd = rsqrtf(q * (1.0f / 256.0f) + 1e-5f);

    float4 gg = *reinterpret_cast<const float4*>(&g[lane * 4]);
    float4 bb = *reinterpret_cast<const float4*>(&bt[lane * 4]);
    float4 y;
    y.x = t0 * rstd * gg.x + bb.x;
    y.y = t1 * rstd * gg.y + bb.y;
    y.z = t2 * rstd * gg.z + bb.z;
    y.w = t3 * rstd * gg.w + bb.w;
    *reinterpret_cast<float4*>(&out[base]) = y;
    short o4[4] = {f2b(y.x), f2b(y.y), f2b(y.z), f2b(y.w)};
    *reinterpret_cast<int2*>(ob + base) = *reinterpret_cast<int2*>(o4);
}

// ---------------------------------------------------------------- launch
extern "C" void kernel_launch(void* const* d_in, const int* in_sizes, int n_in,
                              void* d_out, int out_size, void* d_ws, size_t ws_size,
                              hipStream_t stream) {
    const float* q_xyz   = (const float*)d_in[0];
    const float* q_feat  = (const float*)d_in[1];
    const float* kv_xyz  = (const float*)d_in[2];
    const float* kv_feat = (const float*)d_in[3];
    const float* W_src   = (const float*)d_in[4];
    const float* W_dst   = (const float*)d_in[5];
    const float* W_lin   = (const float*)d_in[6];
    const float* W_attn  = (const float*)d_in[7];
    const float* b_attn  = (const float*)d_in[8];
    const float* W1      = (const float*)d_in[9];
    const float* b1      = (const float*)d_in[10];
    const float* W2      = (const float*)d_in[11];
    const float* b2      = (const float*)d_in[12];
    const float* ln1_g   = (const float*)d_in[13];
    const float* ln1_b   = (const float*)d_in[14];
    const float* ln2_g   = (const float*)d_in[15];
    const float* ln2_b   = (const float*)d_in[16];

    float* out = (float*)d_out;
    char* wsb = (char*)d_ws;
    const size_t MB = (size_t)1 << 20;
    int*   idxb   = (int*)(wsb);                 // 1 MB
    float* validb = (float*)(wsb + 1 * MB);      // 1 MB
    short* kvf16  = (short*)(wsb + 2 * MB);      // 8 MB
    short* outb16 = (short*)(wsb + 10 * MB);     // 8 MB
    short* asrc16 = (short*)(wsb + 18 * MB);     // 8 MB
    short* adst16 = (short*)(wsb + 26 * MB);     // 8 MB
    short* v16    = (short*)(wsb + 34 * MB);     // 8 MB
    short* h16    = (short*)(wsb + 42 * MB);     // 32 MB
    float* convb  = (float*)(wsb + 74 * MB);     // 16 MB
    short* WsrcT  = (short*)(wsb + 90 * MB);     // 256 KB  (NL x 256x256 bf16)
    short* WdstT  = (short*)(wsb + 90 * MB + 256 * 1024);
    short* WlinT  = (short*)(wsb + 90 * MB + 512 * 1024);
    short* WatT   = (short*)(wsb + 90 * MB + 768 * 1024);
    short* W1T    = (short*)(wsb + 91 * MB);     // 1 MB (NL x 1024x256 bf16)
    short* W2T    = (short*)(wsb + 92 * MB);     // 1 MB (NL x 256x1024 bf16)

    const int M = BB * NN;                       // 16384

    init_k<<<M * CC / (256 * 4), 256, 0, stream>>>(q_feat, out, outb16);
    f2b_k<<<M * CC / (256 * 4), 256, 0, stream>>>(kv_feat, kvf16);
    knn_k<<<BB * (NN / 64), 256, 0, stream>>>(q_xyz, kv_xyz, idxb, validb);

    for (int i = 0; i < NL; ++i) {
        const size_t oC = (size_t)i * CC * CC;
        const size_t oF = (size_t)i * CC * CC * FF;
        tconv_k<<<dim3(8, 8),  256, 0, stream>>>(W_src + oC,  WsrcT + oC, CC, CC);
        tconv_k<<<dim3(8, 8),  256, 0, stream>>>(W_dst + oC,  WdstT + oC, CC, CC);
        tconv_k<<<dim3(8, 8),  256, 0, stream>>>(W_lin + oC,  WlinT + oC, CC, CC);
        tconv_k<<<dim3(8, 8),  256, 0, stream>>>(W_attn + oC, WatT  + oC, CC, CC);
        tconv_k<<<dim3(32, 8), 256, 0, stream>>>(W1 + oF, W1T + oF, CC, CC * FF);
        tconv_k<<<dim3(8, 32), 256, 0, stream>>>(W2 + oF, W2T + oF, CC * FF, CC);
    }

    for (int i = 0; i < NL; ++i) {
        const size_t oC = (size_t)i * CC * CC;
        const size_t oF = (size_t)i * CC * CC * FF;
        const float* bat = b_attn + (size_t)i * CC;
        const float* b1p = b1 + (size_t)i * CC * FF;
        const float* b2p = b2 + (size_t)i * CC;

        mm_k<0, 1><<<dim3(2, 128), 256, 0, stream>>>(kvf16,  WsrcT + oC, nullptr, asrc16, M, CC, CC);
        mm_k<0, 1><<<dim3(2, 128), 256, 0, stream>>>(outb16, WdstT + oC, nullptr, adst16, M, CC, CC);
        mm_k<0, 1><<<dim3(2, 128), 256, 0, stream>>>(kvf16,  WlinT + oC, nullptr, v16,    M, CC, CC);

        attn_k<<<dim3(2, M / 8), 256, 0, stream>>>(adst16, asrc16, v16, idxb, validb,
                                                   WatT + oC, bat, convb);
        add_ln_k<<<M / 4, 256, 0, stream>>>(out, convb,
                                            ln1_g + (size_t)i * CC, ln1_b + (size_t)i * CC, outb16);

        mm_k<1, 1><<<dim3(8, 128), 256, 0, stream>>>(outb16, W1T + oF, b1p, h16, M, CC * FF, CC);
        mm_k<0, 0><<<dim3(2, 128), 256, 0, stream>>>(h16, W2T + oF, b2p, convb, M, CC, CC * FF);
        add_ln_k<<<M / 4, 256, 0, stream>>>(out, convb,
                                            ln2_g + (size_t)i * CC, ln2_b + (size_t)i * CC, outb16);
    }
    (void)in_sizes; (void)n_in; (void)out_size; (void)ws_size;
}

// Round 5
// 581.583 us; speedup vs baseline: 4.2919x; 1.0719x over previous
//
#include <hip/hip_runtime.h>
#include <math.h>

#define BB 8
#define NN 2048
#define LL 2048
#define CC 256
#define KK 16
#define NL 2
#define FF 4

typedef __attribute__((ext_vector_type(8))) short short8v;
typedef __attribute__((ext_vector_type(4))) float f32x4;

__device__ __forceinline__ short f2b(float f) {
    unsigned u = __float_as_uint(f);
    u += 0x7FFFu + ((u >> 16) & 1u);
    return (short)(u >> 16);
}
__device__ __forceinline__ float b2f(short s) {
    return __uint_as_float(((unsigned)(unsigned short)s) << 16);
}

// ---------------------------------------------------------------- init: out=q_feat (f32 + bf16 mirror)
__global__ __launch_bounds__(256) void init_k(const float* __restrict__ src,
                                              float* __restrict__ dst,
                                              short* __restrict__ dstb) {
    size_t i = ((size_t)blockIdx.x * 256 + threadIdx.x) * 4;
    float4 v = *reinterpret_cast<const float4*>(src + i);
    *reinterpret_cast<float4*>(dst + i) = v;
    short o[4] = {f2b(v.x), f2b(v.y), f2b(v.z), f2b(v.w)};
    *reinterpret_cast<int2*>(dstb + i) = *reinterpret_cast<int2*>(o);
}

__global__ __launch_bounds__(256) void f2b_k(const float* __restrict__ in,
                                             short* __restrict__ out) {
    size_t i = ((size_t)blockIdx.x * 256 + threadIdx.x) * 4;
    float4 v = *reinterpret_cast<const float4*>(in + i);
    short o[4] = {f2b(v.x), f2b(v.y), f2b(v.z), f2b(v.w)};
    *reinterpret_cast<int2*>(out + i) = *reinterpret_cast<int2*>(o);
}

// W [K][N] fp32 -> Wt [N][K] bf16
__global__ __launch_bounds__(256) void tconv_k(const float* __restrict__ W,
                                               short* __restrict__ Wt,
                                               int K, int N) {
    __shared__ float tile[32][33];
    const int n0 = blockIdx.x * 32, k0 = blockIdx.y * 32;
    const int tx = threadIdx.x & 31, ty = threadIdx.x >> 5;
#pragma unroll
    for (int r = 0; r < 32; r += 8)
        tile[ty + r][tx] = W[(size_t)(k0 + ty + r) * N + n0 + tx];
    __syncthreads();
#pragma unroll
    for (int r = 0; r < 32; r += 8)
        Wt[(size_t)(n0 + ty + r) * K + k0 + tx] = f2b(tile[tx][ty + r]);
}

// ---------------------------------------------------------------- knn (ball query via threshold filter)
// Only in-ball (d2 <= R^2) points matter: out-of-ball top-k members get zero
// attention weight. Scan with threshold -> rare LDS-atomic append of packed
// (d2|idx) u64; leader does deterministic 16-pass min-extract (ties -> lower
// idx, matching top_k). 8 thr/query, 32 queries/block, 512 blocks.
#define QPB 32
#define CAP 48
__global__ __launch_bounds__(256) void knn_k(const float* __restrict__ qxyz,
                                             const float* __restrict__ kvxyz,
                                             int* __restrict__ idx,
                                             float* __restrict__ valid) {
    __shared__ float4 sxyz[LL];                       // 32 KB
    __shared__ unsigned long long cpk[QPB][CAP];      // 12 KB
    __shared__ int ccnt[QPB];

    const int t   = threadIdx.x;
    const int q   = t >> 3;              // local query 0..31
    const int sub = t & 7;
    const int b   = blockIdx.x >> 6;     // 64 blocks per batch
    const int n   = ((blockIdx.x & 63) << 5) + q;

    const float* kb = kvxyz + (size_t)b * LL * 3;
    for (int p = t; p < LL; p += 256)
        sxyz[p] = make_float4(kb[3 * p], kb[3 * p + 1], kb[3 * p + 2], 0.f);
    if (t < QPB) ccnt[t] = 0;
    __syncthreads();

    const size_t qo = (size_t)(b * NN + n) * 3;
    const float qx = qxyz[qo], qy = qxyz[qo + 1], qz = qxyz[qo + 2];
    const float rad2 = (float)(0.12 * 0.12);

    for (int j = sub; j < LL; j += 32) {
        float4 p0 = sxyz[j];
        float4 p1 = sxyz[j + 8];
        float4 p2 = sxyz[j + 16];
        float4 p3 = sxyz[j + 24];
        float x0 = qx - p0.x, y0 = qy - p0.y, z0 = qz - p0.z;
        float x1 = qx - p1.x, y1 = qy - p1.y, z1 = qz - p1.z;
        float x2 = qx - p2.x, y2 = qy - p2.y, z2 = qz - p2.z;
        float x3 = qx - p3.x, y3 = qy - p3.y, z3 = qz - p3.z;
        float d0 = fmaf(x0, x0, fmaf(y0, y0, z0 * z0));
        float d1 = fmaf(x1, x1, fmaf(y1, y1, z1 * z1));
        float d2 = fmaf(x2, x2, fmaf(y2, y2, z2 * z2));
        float d3 = fmaf(x3, x3, fmaf(y3, y3, z3 * z3));
        if (fminf(fminf(d0, d1), fminf(d2, d3)) <= rad2) {
            if (d0 <= rad2) {
                int s = atomicAdd(&ccnt[q], 1);
                if (s < CAP) cpk[q][s] = ((unsigned long long)__float_as_uint(d0) << 32) | (unsigned)(j);
            }
            if (d1 <= rad2) {
                int s = atomicAdd(&ccnt[q], 1);
                if (s < CAP) cpk[q][s] = ((unsigned long long)__float_as_uint(d1) << 32) | (unsigned)(j + 8);
            }
            if (d2 <= rad2) {
                int s = atomicAdd(&ccnt[q], 1);
                if (s < CAP) cpk[q][s] = ((unsigned long long)__float_as_uint(d2) << 32) | (unsigned)(j + 16);
            }
            if (d3 <= rad2) {
                int s = atomicAdd(&ccnt[q], 1);
                if (s < CAP) cpk[q][s] = ((unsigned long long)__float_as_uint(d3) << 32) | (unsigned)(j + 24);
            }
        }
    }
    __syncthreads();

    if (sub == 0) {
        int c = ccnt[q]; c = (c > CAP) ? CAP : c;
        const size_t o = (size_t)(b * NN + n) * KK;
        unsigned long long local[CAP];
        for (int j = 0; j < c; ++j) local[j] = cpk[q][j];
#pragma unroll
        for (int k = 0; k < KK; ++k) {
            unsigned long long best = ~0ull;
            int bj = -1;
            for (int j = 0; j < c; ++j)
                if (local[j] < best) { best = local[j]; bj = j; }
            if (bj >= 0) {
                local[bj] = ~0ull;
                idx[o + k]   = (int)(best & 0xffffffffu);
                valid[o + k] = 1.0f;
            } else {
                idx[o + k]   = 0;
                valid[o + k] = 0.0f;
            }
        }
    }
}

// ---------------------------------------------------------------- bf16 MFMA GEMM
// C[M,N] = act(A[M,Kd] @ Bt[N,Kd]^T + bias). 128x128 tile, 4 waves (2x2),
// each wave 64x64 = 4x4 fragments of mfma_f32_16x16x32_bf16.
template <int ACT, int OBF>
__global__ __launch_bounds__(256) void mm_k(const short* __restrict__ A,
                                            const short* __restrict__ Bt,
                                            const float* __restrict__ bias,
                                            void* __restrict__ Cout,
                                            int M, int N, int Kd) {
    __shared__ __align__(16) short As[128 * 32];
    __shared__ __align__(16) short Bs[128 * 32];
    const int t = threadIdx.x;
    const int lane = t & 63;
    const int wv = t >> 6;
    const int wr = wv >> 1, wc = wv & 1;
    const int lrow = lane & 15;
    const int kc = lane >> 4;
    const int row0 = blockIdx.y * 128;
    const int col0 = blockIdx.x * 128;

    f32x4 acc[4][4];
#pragma unroll
    for (int m = 0; m < 4; ++m)
#pragma unroll
        for (int n = 0; n < 4; ++n) acc[m][n] = f32x4{0.f, 0.f, 0.f, 0.f};

    const int r0 = t >> 2, cch = t & 3;
    const int r1 = r0 + 64;

    for (int k0 = 0; k0 < Kd; k0 += 32) {
        __syncthreads();
        {
            int4 va = *(const int4*)(A  + (size_t)(row0 + r0) * Kd + k0 + cch * 8);
            int4 vb = *(const int4*)(Bt + (size_t)(col0 + r0) * Kd + k0 + cch * 8);
            *(int4*)(As + r0 * 32 + ((cch ^ ((r0 >> 1) & 3)) * 8)) = va;
            *(int4*)(Bs + r0 * 32 + ((cch ^ ((r0 >> 1) & 3)) * 8)) = vb;
            int4 va2 = *(const int4*)(A  + (size_t)(row0 + r1) * Kd + k0 + cch * 8);
            int4 vb2 = *(const int4*)(Bt + (size_t)(col0 + r1) * Kd + k0 + cch * 8);
            *(int4*)(As + r1 * 32 + ((cch ^ ((r1 >> 1) & 3)) * 8)) = va2;
            *(int4*)(Bs + r1 * 32 + ((cch ^ ((r1 >> 1) & 3)) * 8)) = vb2;
        }
        __syncthreads();
        short8v af[4], bf[4];
#pragma unroll
        for (int m = 0; m < 4; ++m) {
            const int ar = wr * 64 + m * 16 + lrow;
            af[m] = *(const short8v*)(As + ar * 32 + ((kc ^ ((ar >> 1) & 3)) * 8));
        }
#pragma unroll
        for (int n = 0; n < 4; ++n) {
            const int br = wc * 64 + n * 16 + lrow;
            bf[n] = *(const short8v*)(Bs + br * 32 + ((kc ^ ((br >> 1) & 3)) * 8));
        }
#pragma unroll
        for (int m = 0; m < 4; ++m)
#pragma unroll
            for (int n = 0; n < 4; ++n)
                acc[m][n] = __builtin_amdgcn_mfma_f32_16x16x32_bf16(
                    af[m], bf[n], acc[m][n], 0, 0, 0);
    }

    float bcol[4];
#pragma unroll
    for (int n = 0; n < 4; ++n)
        bcol[n] = bias ? bias[col0 + wc * 64 + n * 16 + lrow] : 0.f;

#pragma unroll
    for (int m = 0; m < 4; ++m) {
#pragma unroll
        for (int n = 0; n < 4; ++n) {
            const int col = col0 + wc * 64 + n * 16 + lrow;
#pragma unroll
            for (int r = 0; r < 4; ++r) {
                const int row = row0 + wr * 64 + m * 16 + kc * 4 + r;
                float v = acc[m][n][r] + bcol[n];
                if (ACT == 1) v = 0.5f * v * (1.0f + erff(v * 0.70710678118654752f));
                if (OBF) ((short*)Cout)[(size_t)row * N + col] = f2b(v);
                else     ((float*)Cout)[(size_t)row * N + col] = v;
            }
        }
    }
}

// ---------------------------------------------------------------- fused attention (MFMA)
__global__ __launch_bounds__(256) void attn_k(
    const short* __restrict__ adst, const short* __restrict__ asrc,
    const short* __restrict__ vf, const int* __restrict__ idx,
    const float* __restrict__ valid, const short* __restrict__ Wat_t,
    const float* __restrict__ bat, float* __restrict__ conv) {
    __shared__ __align__(16) short smem[128 * 136];  // vt; first 8192 = As|Bs
    __shared__ int   sidx[128];
    __shared__ float sval[128];
    short* As = smem;
    short* Bs = smem + 4096;

    const int t = threadIdx.x;
    const int lane = t & 63;
    const int wv = t >> 6, wr = wv >> 1, wc = wv & 1;
    const int lrow = lane & 15, kc = lane >> 4;
    const int bn0 = blockIdx.y * 8;
    const int c0 = blockIdx.x * 128;
    const size_t boff = (size_t)(bn0 >> 11) * LL;   // batch row offset into [B*L][C]

    if (t < 128) {
        sidx[t] = idx[(size_t)bn0 * KK + t];
        sval[t] = valid[(size_t)bn0 * KK + t];
    }

    f32x4 acc[4][4];
#pragma unroll
    for (int m = 0; m < 4; ++m)
#pragma unroll
        for (int n = 0; n < 4; ++n) acc[m][n] = f32x4{0.f, 0.f, 0.f, 0.f};

    __syncthreads();

    const int r0 = t >> 2, cch = t & 3;
    const int r1 = r0 + 64;

    for (int k0 = 0; k0 < CC; k0 += 32) {
        __syncthreads();
        {
            int bn = bn0 + (r0 >> 4);
            int sj = sidx[r0];
            int4 dd = *(const int4*)(adst + (size_t)bn * CC + k0 + cch * 8);
            int4 ss = *(const int4*)(asrc + (boff + sj) * CC + k0 + cch * 8);
            const short* dp = (const short*)&dd;
            const short* sp = (const short*)&ss;
            short o[8];
#pragma unroll
            for (int e = 0; e < 8; ++e) o[e] = f2b(b2f(dp[e]) - b2f(sp[e]));
            *(int4*)(As + r0 * 32 + ((cch ^ ((r0 >> 1) & 3)) * 8)) = *(int4*)o;

            int bn2 = bn0 + (r1 >> 4);
            int sj2 = sidx[r1];
            int4 dd2 = *(const int4*)(adst + (size_t)bn2 * CC + k0 + cch * 8);
            int4 ss2 = *(const int4*)(asrc + (boff + sj2) * CC + k0 + cch * 8);
            const short* dp2 = (const short*)&dd2;
            const short* sp2 = (const short*)&ss2;
            short o2[8];
#pragma unroll
            for (int e = 0; e < 8; ++e) o2[e] = f2b(b2f(dp2[e]) - b2f(sp2[e]));
            *(int4*)(As + r1 * 32 + ((cch ^ ((r1 >> 1) & 3)) * 8)) = *(int4*)o2;

            int4 vb = *(const int4*)(Wat_t + (size_t)(c0 + r0) * CC + k0 + cch * 8);
            *(int4*)(Bs + r0 * 32 + ((cch ^ ((r0 >> 1) & 3)) * 8)) = vb;
            int4 vb2 = *(const int4*)(Wat_t + (size_t)(c0 + r1) * CC + k0 + cch * 8);
            *(int4*)(Bs + r1 * 32 + ((cch ^ ((r1 >> 1) & 3)) * 8)) = vb2;
        }
        __syncthreads();
        short8v af[4], bf[4];
#pragma unroll
        for (int m = 0; m < 4; ++m) {
            const int ar = wr * 64 + m * 16 + lrow;
            af[m] = *(const short8v*)(As + ar * 32 + ((kc ^ ((ar >> 1) & 3)) * 8));
        }
#pragma unroll
        for (int n = 0; n < 4; ++n) {
            const int br = wc * 64 + n * 16 + lrow;
            bf[n] = *(const short8v*)(Bs + br * 32 + ((kc ^ ((br >> 1) & 3)) * 8));
        }
#pragma unroll
        for (int m = 0; m < 4; ++m)
#pragma unroll
            for (int n = 0; n < 4; ++n)
                acc[m][n] = __builtin_amdgcn_mfma_f32_16x16x32_bf16(
                    af[m], bf[n], acc[m][n], 0, 0, 0);
    }

    __syncthreads();
#pragma unroll
    for (int p = 0; p < 8; ++p) {
        const int q = t + 256 * p;
        const int row = q >> 4, ch = q & 15;
        const int sj = sidx[row];
        int4 vv = *(const int4*)(vf + (boff + sj) * CC + c0 + ch * 8);
        *(int4*)(smem + row * 136 + ch * 8) = vv;
    }
    __syncthreads();

    float bcol[4];
#pragma unroll
    for (int n = 0; n < 4; ++n)
        bcol[n] = bat[c0 + wc * 64 + n * 16 + lrow];

#pragma unroll
    for (int m = 0; m < 4; ++m) {
        const int ql = wr * 4 + m;
#pragma unroll
        for (int n = 0; n < 4; ++n) {
            const int ctile = wc * 64 + n * 16 + lrow;
            float l[4];
#pragma unroll
            for (int r = 0; r < 4; ++r) {
                const int k = kc * 4 + r;
                float a = fmaxf(acc[m][n][r] + bcol[n], 0.f);
                l[r] = (sval[ql * 16 + k] > 0.5f) ? a : -1e9f;
            }
            float mx = fmaxf(fmaxf(l[0], l[1]), fmaxf(l[2], l[3]));
            mx = fmaxf(mx, __shfl_xor(mx, 16));
            mx = fmaxf(mx, __shfl_xor(mx, 32));
            float s = 0.f, num = 0.f;
#pragma unroll
            for (int r = 0; r < 4; ++r) {
                const int k = kc * 4 + r;
                const float e = (l[r] > -5e8f) ? __expf(l[r] - mx) : 0.f;
                s += e;
                num = fmaf(e, b2f(smem[(ql * 16 + k) * 136 + ctile]), num);
            }
            s += __shfl_xor(s, 16);  s += __shfl_xor(s, 32);
            num += __shfl_xor(num, 16); num += __shfl_xor(num, 32);
            if (kc == 0)
                conv[(size_t)(bn0 + ql) * CC + c0 + ctile] = (s > 0.f) ? num / s : 0.f;
        }
    }
}

// ---------------------------------------------------------------- residual + LN (+ bf16 mirror)
__global__ __launch_bounds__(256) void add_ln_k(float* __restrict__ out,
                                                const float* __restrict__ del,
                                                const float* __restrict__ g,
                                                const float* __restrict__ bt,
                                                short* __restrict__ ob) {
    const int row  = blockIdx.x * 4 + (threadIdx.x >> 6);
    const int lane = threadIdx.x & 63;
    const size_t base = (size_t)row * CC + lane * 4;
    float4 x = *reinterpret_cast<const float4*>(&out[base]);
    float4 d = *reinterpret_cast<const float4*>(&del[base]);
    float v0 = x.x + d.x, v1 = x.y + d.y, v2 = x.z + d.z, v3 = x.w + d.w;

    float s = v0 + v1 + v2 + v3;
#pragma unroll
    for (int o = 32; o > 0; o >>= 1) s += __shfl_xor(s, o);
    const float mu = s * (1.0f / 256.0f);
    const float t0 = v0 - mu, t1 = v1 - mu, t2 = v2 - mu, t3 = v3 - mu;
    float q = t0 * t0 + t1 * t1 + t2 * t2 + t3 * t3;
#pragma unroll
    for (int o = 32; o > 0; o >>= 1) q += __shfl_xor(q, o);
    const float rstd = rsqrtf(q * (1.0f / 256.0f) + 1e-5f);

    float4 gg = *reinterpret_cast<const float4*>(&g[lane * 4]);
    float4 bb = *reinterpret_cast<const float4*>(&bt[lane * 4]);
    float4 y;
    y.x = t0 * rstd * gg.x + bb.x;
    y.y = t1 * rstd * gg.y + bb.y;
    y.z = t2 * rstd * gg.z + bb.z;
    y.w = t3 * rstd * gg.w + bb.w;
    *reinterpret_cast<float4*>(&out[base]) = y;
    short o4[4] = {f2b(y.x), f2b(y.y), f2b(y.z), f2b(y.w)};
    *reinterpret_cast<int2*>(ob + base) = *reinterpret_cast<int2*>(o4);
}

// ---------------------------------------------------------------- launch
extern "C" void kernel_launch(void* const* d_in, const int* in_sizes, int n_in,
                              void* d_out, int out_size, void* d_ws, size_t ws_size,
                              hipStream_t stream) {
    const float* q_xyz   = (const float*)d_in[0];
    const float* q_feat  = (const float*)d_in[1];
    const float* kv_xyz  = (const float*)d_in[2];
    const float* kv_feat = (const float*)d_in[3];
    const float* W_src   = (const float*)d_in[4];
    const float* W_dst   = (const float*)d_in[5];
    const float* W_lin   = (const float*)d_in[6];
    const float* W_attn  = (const float*)d_in[7];
    const float* b_attn  = (const float*)d_in[8];
    const float* W1      = (const float*)d_in[9];
    const float* b1      = (const float*)d_in[10];
    const float* W2      = (const float*)d_in[11];
    const float* b2      = (const float*)d_in[12];
    const float* ln1_g   = (const float*)d_in[13];
    const float* ln1_b   = (const float*)d_in[14];
    const float* ln2_g   = (const float*)d_in[15];
    const float* ln2_b   = (const float*)d_in[16];

    float* out = (float*)d_out;
    char* wsb = (char*)d_ws;
    const size_t MB = (size_t)1 << 20;
    int*   idxb   = (int*)(wsb);                 // 1 MB
    float* validb = (float*)(wsb + 1 * MB);      // 1 MB
    short* kvf16  = (short*)(wsb + 2 * MB);      // 8 MB
    short* outb16 = (short*)(wsb + 10 * MB);     // 8 MB
    short* asrc16 = (short*)(wsb + 18 * MB);     // 8 MB
    short* adst16 = (short*)(wsb + 26 * MB);     // 8 MB
    short* v16    = (short*)(wsb + 34 * MB);     // 8 MB
    short* h16    = (short*)(wsb + 42 * MB);     // 32 MB
    float* convb  = (float*)(wsb + 74 * MB);     // 16 MB
    short* WsrcT  = (short*)(wsb + 90 * MB);     // 256 KB  (NL x 256x256 bf16)
    short* WdstT  = (short*)(wsb + 90 * MB + 256 * 1024);
    short* WlinT  = (short*)(wsb + 90 * MB + 512 * 1024);
    short* WatT   = (short*)(wsb + 90 * MB + 768 * 1024);
    short* W1T    = (short*)(wsb + 91 * MB);     // 1 MB (NL x 1024x256 bf16)
    short* W2T    = (short*)(wsb + 92 * MB);     // 1 MB (NL x 256x1024 bf16)

    const int M = BB * NN;                       // 16384

    init_k<<<M * CC / (256 * 4), 256, 0, stream>>>(q_feat, out, outb16);
    f2b_k<<<M * CC / (256 * 4), 256, 0, stream>>>(kv_feat, kvf16);
    knn_k<<<BB * (NN / QPB), 256, 0, stream>>>(q_xyz, kv_xyz, idxb, validb);

    for (int i = 0; i < NL; ++i) {
        const size_t oC = (size_t)i * CC * CC;
        const size_t oF = (size_t)i * CC * CC * FF;
        tconv_k<<<dim3(8, 8),  256, 0, stream>>>(W_src + oC,  WsrcT + oC, CC, CC);
        tconv_k<<<dim3(8, 8),  256, 0, stream>>>(W_dst + oC,  WdstT + oC, CC, CC);
        tconv_k<<<dim3(8, 8),  256, 0, stream>>>(W_lin + oC,  WlinT + oC, CC, CC);
        tconv_k<<<dim3(8, 8),  256, 0, stream>>>(W_attn + oC, WatT  + oC, CC, CC);
        tconv_k<<<dim3(32, 8), 256, 0, stream>>>(W1 + oF, W1T + oF, CC, CC * FF);
        tconv_k<<<dim3(8, 32), 256, 0, stream>>>(W2 + oF, W2T + oF, CC * FF, CC);
    }

    for (int i = 0; i < NL; ++i) {
        const size_t oC = (size_t)i * CC * CC;
        const size_t oF = (size_t)i * CC * CC * FF;
        const float* bat = b_attn + (size_t)i * CC;
        const float* b1p = b1 + (size_t)i * CC * FF;
        const float* b2p = b2 + (size_t)i * CC;

        mm_k<0, 1><<<dim3(2, 128), 256, 0, stream>>>(kvf16,  WsrcT + oC, nullptr, asrc16, M, CC, CC);
        mm_k<0, 1><<<dim3(2, 128), 256, 0, stream>>>(outb16, WdstT + oC, nullptr, adst16, M, CC, CC);
        mm_k<0, 1><<<dim3(2, 128), 256, 0, stream>>>(kvf16,  WlinT + oC, nullptr, v16,    M, CC, CC);

        attn_k<<<dim3(2, M / 8), 256, 0, stream>>>(adst16, asrc16, v16, idxb, validb,
                                                   WatT + oC, bat, convb);
        add_ln_k<<<M / 4, 256, 0, stream>>>(out, convb,
                                            ln1_g + (size_t)i * CC, ln1_b + (size_t)i * CC, outb16);

        mm_k<1, 1><<<dim3(8, 128), 256, 0, stream>>>(outb16, W1T + oF, b1p, h16, M, CC * FF, CC);
        mm_k<0, 0><<<dim3(2, 128), 256, 0, stream>>>(h16, W2T + oF, b2p, convb, M, CC, CC * FF);
        add_ln_k<<<M / 4, 256, 0, stream>>>(out, convb,
                                            ln2_g + (size_t)i * CC, ln2_b + (size_t)i * CC, outb16);
    }
    (void)in_sizes; (void)n_in; (void)out_size; (void)ws_size;
}

// Round 6
// 396.679 us; speedup vs baseline: 6.2925x; 1.4661x over previous
//
#include <hip/hip_runtime.h>
#include <math.h>

#define BB 8
#define NN 2048
#define LL 2048
#define CC 256
#define KK 16
#define NL 2
#define FF 4

typedef __attribute__((ext_vector_type(8))) short short8v;
typedef __attribute__((ext_vector_type(4))) float f32x4;

__device__ __forceinline__ short f2b(float f) {
    unsigned u = __float_as_uint(f);
    u += 0x7FFFu + ((u >> 16) & 1u);
    return (short)(u >> 16);
}
__device__ __forceinline__ float b2f(short s) {
    return __uint_as_float(((unsigned)(unsigned short)s) << 16);
}

// ---------------------------------------------------------------- init: out=q_feat (f32 + bf16 mirror)
__global__ __launch_bounds__(256) void init_k(const float* __restrict__ src,
                                              float* __restrict__ dst,
                                              short* __restrict__ dstb) {
    size_t i = ((size_t)blockIdx.x * 256 + threadIdx.x) * 4;
    float4 v = *reinterpret_cast<const float4*>(src + i);
    *reinterpret_cast<float4*>(dst + i) = v;
    short o[4] = {f2b(v.x), f2b(v.y), f2b(v.z), f2b(v.w)};
    *reinterpret_cast<int2*>(dstb + i) = *reinterpret_cast<int2*>(o);
}

__global__ __launch_bounds__(256) void f2b_k(const float* __restrict__ in,
                                             short* __restrict__ out) {
    size_t i = ((size_t)blockIdx.x * 256 + threadIdx.x) * 4;
    float4 v = *reinterpret_cast<const float4*>(in + i);
    short o[4] = {f2b(v.x), f2b(v.y), f2b(v.z), f2b(v.w)};
    *reinterpret_cast<int2*>(out + i) = *reinterpret_cast<int2*>(o);
}

// W [K][N] fp32 -> Wt [N][K] bf16
__global__ __launch_bounds__(256) void tconv_k(const float* __restrict__ W,
                                               short* __restrict__ Wt,
                                               int K, int N) {
    __shared__ float tile[32][33];
    const int n0 = blockIdx.x * 32, k0 = blockIdx.y * 32;
    const int tx = threadIdx.x & 31, ty = threadIdx.x >> 5;
#pragma unroll
    for (int r = 0; r < 32; r += 8)
        tile[ty + r][tx] = W[(size_t)(k0 + ty + r) * N + n0 + tx];
    __syncthreads();
#pragma unroll
    for (int r = 0; r < 32; r += 8)
        Wt[(size_t)(n0 + ty + r) * K + k0 + tx] = f2b(tile[tx][ty + r]);
}

// ---------------------------------------------------------------- knn (ball query via threshold filter)
// Threshold scan -> rare LDS-atomic append of packed (d2|idx); leader does
// 16-pass min-extract DIRECTLY ON LDS (no private array -> no scratch).
#define QPB 32
#define CAP 48
__global__ __launch_bounds__(256) void knn_k(const float* __restrict__ qxyz,
                                             const float* __restrict__ kvxyz,
                                             int* __restrict__ idx,
                                             float* __restrict__ valid) {
    __shared__ float4 sxyz[LL];                       // 32 KB
    __shared__ unsigned long long cpk[QPB][CAP];      // 12 KB
    __shared__ int ccnt[QPB];

    const int t   = threadIdx.x;
    const int q   = t >> 3;              // local query 0..31
    const int sub = t & 7;
    const int b   = blockIdx.x >> 6;     // 64 blocks per batch
    const int n   = ((blockIdx.x & 63) << 5) + q;

    const float* kb = kvxyz + (size_t)b * LL * 3;
    for (int p = t; p < LL; p += 256)
        sxyz[p] = make_float4(kb[3 * p], kb[3 * p + 1], kb[3 * p + 2], 0.f);
    if (t < QPB) ccnt[t] = 0;
    __syncthreads();

    const size_t qo = (size_t)(b * NN + n) * 3;
    const float qx = qxyz[qo], qy = qxyz[qo + 1], qz = qxyz[qo + 2];
    const float rad2 = (float)(0.12 * 0.12);

    for (int j = sub; j < LL; j += 32) {
        float4 p0 = sxyz[j];
        float4 p1 = sxyz[j + 8];
        float4 p2 = sxyz[j + 16];
        float4 p3 = sxyz[j + 24];
        float x0 = qx - p0.x, y0 = qy - p0.y, z0 = qz - p0.z;
        float x1 = qx - p1.x, y1 = qy - p1.y, z1 = qz - p1.z;
        float x2 = qx - p2.x, y2 = qy - p2.y, z2 = qz - p2.z;
        float x3 = qx - p3.x, y3 = qy - p3.y, z3 = qz - p3.z;
        float d0 = fmaf(x0, x0, fmaf(y0, y0, z0 * z0));
        float d1 = fmaf(x1, x1, fmaf(y1, y1, z1 * z1));
        float d2 = fmaf(x2, x2, fmaf(y2, y2, z2 * z2));
        float d3 = fmaf(x3, x3, fmaf(y3, y3, z3 * z3));
        if (fminf(fminf(d0, d1), fminf(d2, d3)) <= rad2) {
            if (d0 <= rad2) {
                int s = atomicAdd(&ccnt[q], 1);
                if (s < CAP) cpk[q][s] = ((unsigned long long)__float_as_uint(d0) << 32) | (unsigned)(j);
            }
            if (d1 <= rad2) {
                int s = atomicAdd(&ccnt[q], 1);
                if (s < CAP) cpk[q][s] = ((unsigned long long)__float_as_uint(d1) << 32) | (unsigned)(j + 8);
            }
            if (d2 <= rad2) {
                int s = atomicAdd(&ccnt[q], 1);
                if (s < CAP) cpk[q][s] = ((unsigned long long)__float_as_uint(d2) << 32) | (unsigned)(j + 16);
            }
            if (d3 <= rad2) {
                int s = atomicAdd(&ccnt[q], 1);
                if (s < CAP) cpk[q][s] = ((unsigned long long)__float_as_uint(d3) << 32) | (unsigned)(j + 24);
            }
        }
    }
    __syncthreads();

    if (sub == 0) {
        int c = ccnt[q]; c = (c > CAP) ? CAP : c;
        const size_t o = (size_t)(b * NN + n) * KK;
#pragma unroll 1
        for (int k = 0; k < KK; ++k) {
            unsigned long long best = ~0ull;
            int bj = -1;
#pragma unroll 1
            for (int j = 0; j < c; ++j) {
                unsigned long long v = cpk[q][j];
                if (v < best) { best = v; bj = j; }
            }
            if (bj >= 0) {
                cpk[q][bj] = ~0ull;
                idx[o + k]   = (int)(best & 0xffffffffu);
                valid[o + k] = 1.0f;
            } else {
                idx[o + k]   = 0;
                valid[o + k] = 0.0f;
            }
        }
    }
}

// ---------------------------------------------------------------- bf16 MFMA GEMM
// C[M,N] = act(A[M,Kd] @ Bt[N,Kd]^T + bias). 128x128 tile, 4 waves (2x2),
// each wave 64x64 = 4x4 fragments of mfma_f32_16x16x32_bf16.
template <int ACT, int OBF>
__global__ __launch_bounds__(256) void mm_k(const short* __restrict__ A,
                                            const short* __restrict__ Bt,
                                            const float* __restrict__ bias,
                                            void* __restrict__ Cout,
                                            int M, int N, int Kd) {
    __shared__ __align__(16) short As[128 * 32];
    __shared__ __align__(16) short Bs[128 * 32];
    const int t = threadIdx.x;
    const int lane = t & 63;
    const int wv = t >> 6;
    const int wr = wv >> 1, wc = wv & 1;
    const int lrow = lane & 15;
    const int kc = lane >> 4;
    const int row0 = blockIdx.y * 128;
    const int col0 = blockIdx.x * 128;

    f32x4 acc[4][4];
#pragma unroll
    for (int m = 0; m < 4; ++m)
#pragma unroll
        for (int n = 0; n < 4; ++n) acc[m][n] = f32x4{0.f, 0.f, 0.f, 0.f};

    const int r0 = t >> 2, cch = t & 3;
    const int r1 = r0 + 64;

    for (int k0 = 0; k0 < Kd; k0 += 32) {
        __syncthreads();
        {
            int4 va = *(const int4*)(A  + (size_t)(row0 + r0) * Kd + k0 + cch * 8);
            int4 vb = *(const int4*)(Bt + (size_t)(col0 + r0) * Kd + k0 + cch * 8);
            *(int4*)(As + r0 * 32 + ((cch ^ ((r0 >> 1) & 3)) * 8)) = va;
            *(int4*)(Bs + r0 * 32 + ((cch ^ ((r0 >> 1) & 3)) * 8)) = vb;
            int4 va2 = *(const int4*)(A  + (size_t)(row0 + r1) * Kd + k0 + cch * 8);
            int4 vb2 = *(const int4*)(Bt + (size_t)(col0 + r1) * Kd + k0 + cch * 8);
            *(int4*)(As + r1 * 32 + ((cch ^ ((r1 >> 1) & 3)) * 8)) = va2;
            *(int4*)(Bs + r1 * 32 + ((cch ^ ((r1 >> 1) & 3)) * 8)) = vb2;
        }
        __syncthreads();
        short8v af[4], bf[4];
#pragma unroll
        for (int m = 0; m < 4; ++m) {
            const int ar = wr * 64 + m * 16 + lrow;
            af[m] = *(const short8v*)(As + ar * 32 + ((kc ^ ((ar >> 1) & 3)) * 8));
        }
#pragma unroll
        for (int n = 0; n < 4; ++n) {
            const int br = wc * 64 + n * 16 + lrow;
            bf[n] = *(const short8v*)(Bs + br * 32 + ((kc ^ ((br >> 1) & 3)) * 8));
        }
#pragma unroll
        for (int m = 0; m < 4; ++m)
#pragma unroll
            for (int n = 0; n < 4; ++n)
                acc[m][n] = __builtin_amdgcn_mfma_f32_16x16x32_bf16(
                    af[m], bf[n], acc[m][n], 0, 0, 0);
    }

    float bcol[4];
#pragma unroll
    for (int n = 0; n < 4; ++n)
        bcol[n] = bias ? bias[col0 + wc * 64 + n * 16 + lrow] : 0.f;

#pragma unroll
    for (int m = 0; m < 4; ++m) {
#pragma unroll
        for (int n = 0; n < 4; ++n) {
            const int col = col0 + wc * 64 + n * 16 + lrow;
#pragma unroll
            for (int r = 0; r < 4; ++r) {
                const int row = row0 + wr * 64 + m * 16 + kc * 4 + r;
                float v = acc[m][n][r] + bcol[n];
                if (ACT == 1) v = 0.5f * v * (1.0f + erff(v * 0.70710678118654752f));
                if (OBF) ((short*)Cout)[(size_t)row * N + col] = f2b(v);
                else     ((float*)Cout)[(size_t)row * N + col] = v;
            }
        }
    }
}

// ---------------------------------------------------------------- attention (gather/elementwise)
// logits[b,n,k,c] = relu(dW[b,n,c] - sW[b,idx,c] + bias[c]); in-thread softmax
// over k; conv = sum_k attn * v_g. Thread = channel, block = 16 queries.
#define AQB 16
__global__ __launch_bounds__(256) void attn2_k(
    const short* __restrict__ dw, const short* __restrict__ sw,
    const short* __restrict__ vf, const int* __restrict__ idx,
    const float* __restrict__ valid, const float* __restrict__ bat,
    float* __restrict__ conv) {
    __shared__ int   sidx[AQB * KK];
    __shared__ float sval[AQB * KK];
    const int t = threadIdx.x;                    // channel
    const int bn0 = blockIdx.x * AQB;
    const size_t boff = (size_t)(bn0 >> 11) * LL; // batch offset into [B*L]

    sidx[t] = idx[(size_t)bn0 * KK + t];
    sval[t] = valid[(size_t)bn0 * KK + t];
    __syncthreads();

    const float bias = bat[t];
#pragma unroll 1
    for (int q = 0; q < AQB; ++q) {
        const int bn = bn0 + q;
        const float d = b2f(dw[(size_t)bn * CC + t]) + bias;
        float l[KK];
        float m = -1e9f;
#pragma unroll
        for (int k = 0; k < KK; ++k) {
            const int j = sidx[q * KK + k];
            float a = fmaxf(d - b2f(sw[(boff + j) * CC + t]), 0.f);
            l[k] = (sval[q * KK + k] > 0.5f) ? a : -1e9f;
            m = fmaxf(m, l[k]);
        }
        float s = 0.f, num = 0.f;
#pragma unroll
        for (int k = 0; k < KK; ++k) {
            const int j = sidx[q * KK + k];
            const float e = (l[k] > -5e8f) ? __expf(l[k] - m) : 0.f;
            s += e;
            num = fmaf(e, b2f(vf[(boff + j) * CC + t]), num);
        }
        conv[(size_t)bn * CC + t] = (s > 0.f) ? num / s : 0.f;
    }
}

// ---------------------------------------------------------------- residual + LN (+ bf16 mirror)
__global__ __launch_bounds__(256) void add_ln_k(float* __restrict__ out,
                                                const float* __restrict__ del,
                                                const float* __restrict__ g,
                                                const float* __restrict__ bt,
                                                short* __restrict__ ob) {
    const int row  = blockIdx.x * 4 + (threadIdx.x >> 6);
    const int lane = threadIdx.x & 63;
    const size_t base = (size_t)row * CC + lane * 4;
    float4 x = *reinterpret_cast<const float4*>(&out[base]);
    float4 d = *reinterpret_cast<const float4*>(&del[base]);
    float v0 = x.x + d.x, v1 = x.y + d.y, v2 = x.z + d.z, v3 = x.w + d.w;

    float s = v0 + v1 + v2 + v3;
#pragma unroll
    for (int o = 32; o > 0; o >>= 1) s += __shfl_xor(s, o);
    const float mu = s * (1.0f / 256.0f);
    const float t0 = v0 - mu, t1 = v1 - mu, t2 = v2 - mu, t3 = v3 - mu;
    float q = t0 * t0 + t1 * t1 + t2 * t2 + t3 * t3;
#pragma unroll
    for (int o = 32; o > 0; o >>= 1) q += __shfl_xor(q, o);
    const float rstd = rsqrtf(q * (1.0f / 256.0f) + 1e-5f);

    float4 gg = *reinterpret_cast<const float4*>(&g[lane * 4]);
    float4 bb = *reinterpret_cast<const float4*>(&bt[lane * 4]);
    float4 y;
    y.x = t0 * rstd * gg.x + bb.x;
    y.y = t1 * rstd * gg.y + bb.y;
    y.z = t2 * rstd * gg.z + bb.z;
    y.w = t3 * rstd * gg.w + bb.w;
    *reinterpret_cast<float4*>(&out[base]) = y;
    short o4[4] = {f2b(y.x), f2b(y.y), f2b(y.z), f2b(y.w)};
    *reinterpret_cast<int2*>(ob + base) = *reinterpret_cast<int2*>(o4);
}

// ---------------------------------------------------------------- launch
extern "C" void kernel_launch(void* const* d_in, const int* in_sizes, int n_in,
                              void* d_out, int out_size, void* d_ws, size_t ws_size,
                              hipStream_t stream) {
    const float* q_xyz   = (const float*)d_in[0];
    const float* q_feat  = (const float*)d_in[1];
    const float* kv_xyz  = (const float*)d_in[2];
    const float* kv_feat = (const float*)d_in[3];
    const float* W_src   = (const float*)d_in[4];
    const float* W_dst   = (const float*)d_in[5];
    const float* W_lin   = (const float*)d_in[6];
    const float* W_attn  = (const float*)d_in[7];
    const float* b_attn  = (const float*)d_in[8];
    const float* W1      = (const float*)d_in[9];
    const float* b1      = (const float*)d_in[10];
    const float* W2      = (const float*)d_in[11];
    const float* b2      = (const float*)d_in[12];
    const float* ln1_g   = (const float*)d_in[13];
    const float* ln1_b   = (const float*)d_in[14];
    const float* ln2_g   = (const float*)d_in[15];
    const float* ln2_b   = (const float*)d_in[16];

    float* out = (float*)d_out;
    char* wsb = (char*)d_ws;
    const size_t MB = (size_t)1 << 20;
    int*   idxb   = (int*)(wsb);                 // 1 MB
    float* validb = (float*)(wsb + 1 * MB);      // 1 MB
    short* kvf16  = (short*)(wsb + 2 * MB);      // 8 MB
    short* outb16 = (short*)(wsb + 10 * MB);     // 8 MB
    short* sw16   = (short*)(wsb + 18 * MB);     // 8 MB
    short* dw16   = (short*)(wsb + 26 * MB);     // 8 MB
    short* v16    = (short*)(wsb + 34 * MB);     // 8 MB
    short* h16    = (short*)(wsb + 42 * MB);     // 32 MB
    float* convb  = (float*)(wsb + 74 * MB);     // 16 MB
    short* WatT   = (short*)(wsb + 90 * MB);                  // 256 KB
    short* Wdst16 = (short*)(wsb + 90 * MB + 256 * 1024);     // 256 KB (row-major bf16)
    short* Wsrc16 = (short*)(wsb + 90 * MB + 512 * 1024);     // 256 KB
    short* WlinT  = (short*)(wsb + 90 * MB + 768 * 1024);     // 256 KB
    short* W1T    = (short*)(wsb + 91 * MB);     // 1 MB
    short* W2T    = (short*)(wsb + 92 * MB);     // 1 MB
    short* WcdT   = (short*)(wsb + 93 * MB);                  // 256 KB (combined)
    short* WcsT   = (short*)(wsb + 93 * MB + 256 * 1024);     // 256 KB

    const int M = BB * NN;                       // 16384

    init_k<<<M * CC / (256 * 4), 256, 0, stream>>>(q_feat, out, outb16);
    f2b_k<<<M * CC / (256 * 4), 256, 0, stream>>>(kv_feat, kvf16);
    knn_k<<<BB * (NN / QPB), 256, 0, stream>>>(q_xyz, kv_xyz, idxb, validb);

    // weight prep: row-major bf16 of W_dst/W_src (both layers at once)
    f2b_k<<<NL * CC * CC / (256 * 4), 256, 0, stream>>>(W_dst, Wdst16);
    f2b_k<<<NL * CC * CC / (256 * 4), 256, 0, stream>>>(W_src, Wsrc16);

    for (int i = 0; i < NL; ++i) {
        const size_t oC = (size_t)i * CC * CC;
        const size_t oF = (size_t)i * CC * CC * FF;
        tconv_k<<<dim3(8, 8),  256, 0, stream>>>(W_attn + oC, WatT + oC, CC, CC);
        tconv_k<<<dim3(8, 8),  256, 0, stream>>>(W_lin + oC,  WlinT + oC, CC, CC);
        tconv_k<<<dim3(32, 8), 256, 0, stream>>>(W1 + oF, W1T + oF, CC, CC * FF);
        tconv_k<<<dim3(8, 32), 256, 0, stream>>>(W2 + oF, W2T + oF, CC * FF, CC);
        // combined weights: WcdT[n][k] = sum_j W_attn[j][n] * W_dst[k][j]
        mm_k<0, 1><<<dim3(2, 2), 256, 0, stream>>>(WatT + oC, Wdst16 + oC, nullptr, WcdT + oC, CC, CC, CC);
        mm_k<0, 1><<<dim3(2, 2), 256, 0, stream>>>(WatT + oC, Wsrc16 + oC, nullptr, WcsT + oC, CC, CC, CC);
    }

    for (int i = 0; i < NL; ++i) {
        const size_t oC = (size_t)i * CC * CC;
        const size_t oF = (size_t)i * CC * CC * FF;
        const float* bat = b_attn + (size_t)i * CC;
        const float* b1p = b1 + (size_t)i * CC * FF;
        const float* b2p = b2 + (size_t)i * CC;

        mm_k<0, 1><<<dim3(2, 128), 256, 0, stream>>>(outb16, WcdT + oC, nullptr, dw16, M, CC, CC);
        mm_k<0, 1><<<dim3(2, 128), 256, 0, stream>>>(kvf16,  WcsT + oC, nullptr, sw16, M, CC, CC);
        mm_k<0, 1><<<dim3(2, 128), 256, 0, stream>>>(kvf16,  WlinT + oC, nullptr, v16,  M, CC, CC);

        attn2_k<<<M / AQB, 256, 0, stream>>>(dw16, sw16, v16, idxb, validb, bat, convb);
        add_ln_k<<<M / 4, 256, 0, stream>>>(out, convb,
                                            ln1_g + (size_t)i * CC, ln1_b + (size_t)i * CC, outb16);

        mm_k<1, 1><<<dim3(8, 128), 256, 0, stream>>>(outb16, W1T + oF, b1p, h16, M, CC * FF, CC);
        mm_k<0, 0><<<dim3(2, 128), 256, 0, stream>>>(h16, W2T + oF, b2p, convb, M, CC, CC * FF);
        add_ln_k<<<M / 4, 256, 0, stream>>>(out, convb,
                                            ln2_g + (size_t)i * CC, ln2_b + (size_t)i * CC, outb16);
    }
    (void)in_sizes; (void)n_in; (void)out_size; (void)ws_size;
}